// Round 1
// baseline (1286.099 us; speedup 1.0000x reference)
//
#include <hip/hip_runtime.h>
#include <math.h>

#define N_NODES 100000
#define N_EDGES 1600000

constexpr int SCAN_B = 1024;

// ---------------- CSR build ----------------

__global__ void hist_kernel(const int* __restrict__ dst, int* __restrict__ deg, int E) {
    int e = blockIdx.x * blockDim.x + threadIdx.x;
    if (e < E) atomicAdd(&deg[dst[e]], 1);
}

__global__ void scan_block_kernel(const int* __restrict__ in, int* __restrict__ out,
                                  int* __restrict__ partials, int n) {
    __shared__ int sh[SCAN_B];
    int gid = blockIdx.x * SCAN_B + threadIdx.x;
    int v = (gid < n) ? in[gid] : 0;
    sh[threadIdx.x] = v;
    __syncthreads();
    for (int off = 1; off < SCAN_B; off <<= 1) {
        int x = (threadIdx.x >= (unsigned)off) ? sh[threadIdx.x - off] : 0;
        __syncthreads();
        sh[threadIdx.x] += x;
        __syncthreads();
    }
    if (gid < n) out[gid] = sh[threadIdx.x];
    if (threadIdx.x == SCAN_B - 1) partials[blockIdx.x] = sh[SCAN_B - 1];
}

__global__ void scan_partials_kernel(int* partials, int nb) {
    __shared__ int sh[SCAN_B];
    int v = (threadIdx.x < (unsigned)nb) ? partials[threadIdx.x] : 0;
    sh[threadIdx.x] = v;
    __syncthreads();
    for (int off = 1; off < SCAN_B; off <<= 1) {
        int x = (threadIdx.x >= (unsigned)off) ? sh[threadIdx.x - off] : 0;
        __syncthreads();
        sh[threadIdx.x] += x;
        __syncthreads();
    }
    if (threadIdx.x < (unsigned)nb) partials[threadIdx.x] = sh[threadIdx.x] - v; // exclusive
}

__global__ void scan_add_kernel(int* out, const int* __restrict__ partials, int n) {
    int gid = blockIdx.x * SCAN_B + threadIdx.x;
    if (gid < n) out[gid] += partials[blockIdx.x];
}

__global__ void scatter_kernel(const int* __restrict__ src, const int* __restrict__ dst,
                               const int* __restrict__ row_ptr, int* __restrict__ fill,
                               int* __restrict__ col, int E) {
    int e = blockIdx.x * blockDim.x + threadIdx.x;
    if (e < E) {
        int d = dst[e];
        int pos = row_ptr[d] + atomicAdd(&fill[d], 1);
        col[pos] = src[e];
    }
}

// ---------------- per-layer GEMM + attention dots ----------------
// block = HD threads, NPB nodes per block. xl[n, t] = sum_k h[n,k] W[k,t];
// asrc[n,h] = <xl[n,h,:], a_s[h,:]>, adst likewise.

template<int DIN, int HD, int D, int NPB>
__global__ void gemm_alpha_kernel(const float* __restrict__ h, const float* __restrict__ W,
                                  const float* __restrict__ a_s, const float* __restrict__ a_d,
                                  float* __restrict__ xl, float* __restrict__ asrc,
                                  float* __restrict__ adst) {
    int node0 = blockIdx.x * NPB;
    int t = threadIdx.x;
    __shared__ float hrow[NPB][DIN];
    for (int idx = t; idx < NPB * DIN; idx += HD) {
        int nn = idx / DIN, k = idx % DIN;
        hrow[nn][k] = h[(size_t)(node0 + nn) * DIN + k];
    }
    __syncthreads();
    float acc[NPB];
#pragma unroll
    for (int nn = 0; nn < NPB; ++nn) acc[nn] = 0.f;
    for (int k = 0; k < DIN; ++k) {
        float w = W[k * HD + t];
#pragma unroll
        for (int nn = 0; nn < NPB; ++nn) acc[nn] += hrow[nn][k] * w;
    }
    int head = t / D, dd = t % D;
    float as_t = a_s[t], ad_t = a_d[t];
#pragma unroll
    for (int nn = 0; nn < NPB; ++nn) {
        xl[(size_t)(node0 + nn) * HD + t] = acc[nn];
        float ps = acc[nn] * as_t;
        float pd = acc[nn] * ad_t;
#pragma unroll
        for (int off = D / 2; off > 0; off >>= 1) {
            ps += __shfl_down(ps, off, D);
            pd += __shfl_down(pd, off, D);
        }
        if (dd == 0) {
            asrc[(node0 + nn) * 2 + head] = ps;
            adst[(node0 + nn) * 2 + head] = pd;
        }
    }
}

// ---------------- aggregation: online segment-softmax + weighted gather ----------------
// one block per destination node; thread = (head, d). Layers 0-2: +bias, ReLU.

template<int HD, int D>
__global__ void aggregate_relu_kernel(const float* __restrict__ xl, const float* __restrict__ asrc,
                                      const float* __restrict__ adst, const int* __restrict__ row_ptr,
                                      const int* __restrict__ col, const float* __restrict__ bias,
                                      float* __restrict__ out) {
    int node = blockIdx.x;
    int t = threadIdx.x;
    int head = t / D;
    float adn = adst[node * 2 + head];
    int beg = row_ptr[node], end = row_ptr[node + 1];
    float m = -INFINITY, s = 0.f, acc = 0.f;
    for (int i = beg; i < end; ++i) {
        int sn = col[i];
        float e = asrc[sn * 2 + head] + adn;
        e = (e >= 0.f) ? e : 0.2f * e;
        float mn = fmaxf(m, e);
        float scale = __expf(m - mn);
        float p = __expf(e - mn);
        s = s * scale + p;
        acc = acc * scale + p * xl[(size_t)sn * HD + t];
        m = mn;
    }
    float o = acc / (s + 1e-16f) + bias[t];
    out[(size_t)node * HD + t] = fmaxf(o, 0.f);
}

// final layer: mean over heads + bias + log_softmax, write d_out
__global__ void aggregate_final_kernel(const float* __restrict__ xl, const float* __restrict__ asrc,
                                       const float* __restrict__ adst, const int* __restrict__ row_ptr,
                                       const int* __restrict__ col, const float* __restrict__ bias,
                                       float* __restrict__ out) {
    constexpr int HD = 64, D = 32;
    int node = blockIdx.x;
    int t = threadIdx.x;  // 0..63, one wave
    int head = t / D;
    float adn = adst[node * 2 + head];
    int beg = row_ptr[node], end = row_ptr[node + 1];
    float m = -INFINITY, s = 0.f, acc = 0.f;
    for (int i = beg; i < end; ++i) {
        int sn = col[i];
        float e = asrc[sn * 2 + head] + adn;
        e = (e >= 0.f) ? e : 0.2f * e;
        float mn = fmaxf(m, e);
        float scale = __expf(m - mn);
        float p = __expf(e - mn);
        s = s * scale + p;
        acc = acc * scale + p * xl[(size_t)sn * HD + t];
        m = mn;
    }
    float o = acc / (s + 1e-16f);
    float other = __shfl_down(o, 32, 64);  // lane t<32 pulls head-1 partner
    if (t < 32) {
        float v = 0.5f * (o + other) + bias[t];
        float mx = v;
#pragma unroll
        for (int off = 16; off > 0; off >>= 1) mx = fmaxf(mx, __shfl_xor(mx, off, 32));
        float ex = __expf(v - mx);
        float sm = ex;
#pragma unroll
        for (int off = 16; off > 0; off >>= 1) sm += __shfl_xor(sm, off, 32);
        out[(size_t)node * 32 + t] = v - mx - logf(sm);
    }
}

// ---------------- launch ----------------

extern "C" void kernel_launch(void* const* d_in, const int* in_sizes, int n_in,
                              void* d_out, int out_size, void* d_ws, size_t ws_size,
                              hipStream_t stream) {
    const int N = N_NODES, E = N_EDGES;

    const float* x  = (const float*)d_in[0];
    const int*  ei  = (const int*)d_in[1];
    const float* W0 = (const float*)d_in[2];
    const float* as0 = (const float*)d_in[3];
    const float* ad0 = (const float*)d_in[4];
    const float* b0 = (const float*)d_in[5];
    const float* W1 = (const float*)d_in[6];
    const float* as1 = (const float*)d_in[7];
    const float* ad1 = (const float*)d_in[8];
    const float* b1 = (const float*)d_in[9];
    const float* W2 = (const float*)d_in[10];
    const float* as2 = (const float*)d_in[11];
    const float* ad2 = (const float*)d_in[12];
    const float* b2 = (const float*)d_in[13];
    const float* W3 = (const float*)d_in[14];
    const float* as3 = (const float*)d_in[15];
    const float* ad3 = (const float*)d_in[16];
    const float* b3 = (const float*)d_in[17];
    float* out = (float*)d_out;

    const int* srcv = ei;       // edge_index[0]
    const int* dstv = ei + E;   // edge_index[1]

    // carve workspace (256B aligned)
    char* p = (char*)d_ws;
    auto carve = [&](size_t bytes) -> void* {
        void* r = (void*)p;
        p += (bytes + 255) & ~(size_t)255;
        return r;
    };
    int* deg      = (int*)carve((size_t)N * 4);
    int* fill     = (int*)carve((size_t)N * 4);
    int* rp       = (int*)carve((size_t)(N + 1) * 4);
    int* col      = (int*)carve((size_t)E * 4);
    int* partials = (int*)carve((size_t)SCAN_B * 4);
    float* bufX   = (float*)carve((size_t)N * 128 * 4);
    float* bufH   = (float*)carve((size_t)N * 128 * 4);
    float* asrc   = (float*)carve((size_t)N * 2 * 4);
    float* adst   = (float*)carve((size_t)N * 2 * 4);

    hipMemsetAsync(deg, 0, (size_t)N * 4, stream);
    hipMemsetAsync(fill, 0, (size_t)N * 4, stream);
    hipMemsetAsync(rp, 0, 4, stream);

    // CSR by destination
    hist_kernel<<<(E + 255) / 256, 256, 0, stream>>>(dstv, deg, E);
    int nb = (N + SCAN_B - 1) / SCAN_B;
    scan_block_kernel<<<nb, SCAN_B, 0, stream>>>(deg, rp + 1, partials, N);
    scan_partials_kernel<<<1, SCAN_B, 0, stream>>>(partials, nb);
    scan_add_kernel<<<nb, SCAN_B, 0, stream>>>(rp + 1, partials, N);
    scatter_kernel<<<(E + 255) / 256, 256, 0, stream>>>(srcv, dstv, rp, fill, col, E);

    constexpr int NPB = 8;  // nodes per block in gemm (N % NPB == 0)

    // layer 0: x[N,128] -> xl bufX, aggregate -> bufH (relu)
    gemm_alpha_kernel<128, 128, 64, NPB><<<N / NPB, 128, 0, stream>>>(x, W0, as0, ad0, bufX, asrc, adst);
    aggregate_relu_kernel<128, 64><<<N, 128, 0, stream>>>(bufX, asrc, adst, rp, col, b0, bufH);
    // layer 1
    gemm_alpha_kernel<128, 128, 64, NPB><<<N / NPB, 128, 0, stream>>>(bufH, W1, as1, ad1, bufX, asrc, adst);
    aggregate_relu_kernel<128, 64><<<N, 128, 0, stream>>>(bufX, asrc, adst, rp, col, b1, bufH);
    // layer 2
    gemm_alpha_kernel<128, 128, 64, NPB><<<N / NPB, 128, 0, stream>>>(bufH, W2, as2, ad2, bufX, asrc, adst);
    aggregate_relu_kernel<128, 64><<<N, 128, 0, stream>>>(bufX, asrc, adst, rp, col, b2, bufH);
    // layer 3: [N,128] @ W3[128,64] -> xl [N,2,32]; mean heads + bias + log_softmax
    gemm_alpha_kernel<128, 64, 32, NPB><<<N / NPB, 64, 0, stream>>>(bufH, W3, as3, ad3, bufX, asrc, adst);
    aggregate_final_kernel<<<N, 64, 0, stream>>>(bufX, asrc, adst, rp, col, b3, out);
}

// Round 2
// 1148.883 us; speedup vs baseline: 1.1194x; 1.1194x over previous
//
#include <hip/hip_runtime.h>
#include <hip/hip_bf16.h>
#include <math.h>

#define N_NODES 100000
#define N_EDGES 1600000

constexpr int SCAN_B = 1024;

// ---------------- CSR build ----------------

__global__ void hist_kernel(const int* __restrict__ dst, int* __restrict__ deg, int E) {
    int e = blockIdx.x * blockDim.x + threadIdx.x;
    if (e < E) atomicAdd(&deg[dst[e]], 1);
}

__global__ void scan_block_kernel(const int* __restrict__ in, int* __restrict__ out,
                                  int* __restrict__ partials, int n) {
    __shared__ int sh[SCAN_B];
    int gid = blockIdx.x * SCAN_B + threadIdx.x;
    int v = (gid < n) ? in[gid] : 0;
    sh[threadIdx.x] = v;
    __syncthreads();
    for (int off = 1; off < SCAN_B; off <<= 1) {
        int x = (threadIdx.x >= (unsigned)off) ? sh[threadIdx.x - off] : 0;
        __syncthreads();
        sh[threadIdx.x] += x;
        __syncthreads();
    }
    if (gid < n) out[gid] = sh[threadIdx.x];
    if (threadIdx.x == SCAN_B - 1) partials[blockIdx.x] = sh[SCAN_B - 1];
}

__global__ void scan_partials_kernel(int* partials, int nb) {
    __shared__ int sh[SCAN_B];
    int v = (threadIdx.x < (unsigned)nb) ? partials[threadIdx.x] : 0;
    sh[threadIdx.x] = v;
    __syncthreads();
    for (int off = 1; off < SCAN_B; off <<= 1) {
        int x = (threadIdx.x >= (unsigned)off) ? sh[threadIdx.x - off] : 0;
        __syncthreads();
        sh[threadIdx.x] += x;
        __syncthreads();
    }
    if (threadIdx.x < (unsigned)nb) partials[threadIdx.x] = sh[threadIdx.x] - v; // exclusive
}

__global__ void scan_add_kernel(int* out, const int* __restrict__ partials, int n) {
    int gid = blockIdx.x * SCAN_B + threadIdx.x;
    if (gid < n) out[gid] += partials[blockIdx.x];
}

__global__ void scatter_kernel(const int* __restrict__ src, const int* __restrict__ dst,
                               const int* __restrict__ row_ptr, int* __restrict__ fill,
                               int* __restrict__ col, int E) {
    int e = blockIdx.x * blockDim.x + threadIdx.x;
    if (e < E) {
        int d = dst[e];
        int pos = row_ptr[d] + atomicAdd(&fill[d], 1);
        col[pos] = src[e];
    }
}

// ---------------- per-layer GEMM + attention dots ----------------
// block = HD threads, NPB nodes per block. xl (bf16) [n, t] = sum_k h[n,k] W[k,t];
// asrc[n,h] = <xl[n,h,:], a_s[h,:]> (fp32), adst likewise.

template<int DIN, int HD, int D, int NPB>
__global__ void gemm_alpha_kernel(const float* __restrict__ h, const float* __restrict__ W,
                                  const float* __restrict__ a_s, const float* __restrict__ a_d,
                                  __hip_bfloat16* __restrict__ xl, float* __restrict__ asrc,
                                  float* __restrict__ adst) {
    constexpr int C4 = DIN / 4;
    int node0 = blockIdx.x * NPB;
    int t = threadIdx.x;
    __shared__ float4 hrow[NPB][C4];
    for (int idx = t; idx < NPB * C4; idx += HD) {
        int nn = idx / C4, kk = idx % C4;
        hrow[nn][kk] = ((const float4*)h)[(size_t)(node0 + nn) * C4 + kk];
    }
    __syncthreads();
    float acc[NPB];
#pragma unroll
    for (int nn = 0; nn < NPB; ++nn) acc[nn] = 0.f;
    for (int kc = 0; kc < C4; ++kc) {
        int kb = 4 * kc;
        float w0 = W[(kb + 0) * HD + t];
        float w1 = W[(kb + 1) * HD + t];
        float w2 = W[(kb + 2) * HD + t];
        float w3 = W[(kb + 3) * HD + t];
#pragma unroll
        for (int nn = 0; nn < NPB; ++nn) {
            float4 hv = hrow[nn][kc];  // b128 broadcast
            acc[nn] = fmaf(hv.w, w3, fmaf(hv.z, w2, fmaf(hv.y, w1, fmaf(hv.x, w0, acc[nn]))));
        }
    }
    int head = t / D, dd = t % D;
    float as_t = a_s[t], ad_t = a_d[t];
#pragma unroll
    for (int nn = 0; nn < NPB; ++nn) {
        xl[(size_t)(node0 + nn) * HD + t] = __float2bfloat16(acc[nn]);
        float ps = acc[nn] * as_t;
        float pd = acc[nn] * ad_t;
#pragma unroll
        for (int off = D / 2; off > 0; off >>= 1) {
            ps += __shfl_down(ps, off, D);
            pd += __shfl_down(pd, off, D);
        }
        if (dd == 0) {
            asrc[(node0 + nn) * 2 + head] = ps;
            adst[(node0 + nn) * 2 + head] = pd;
        }
    }
}

// ---------------- aggregation: two-pass segment-softmax + weighted bf16 gather ----------------
// one wave (64 threads) per destination node; lane t handles column pair (2t, 2t+1).
// HD=128 columns -> 64 bfloat162 per row; head = t/32.

__global__ void aggregate_relu_bf16(const __hip_bfloat162* __restrict__ xl2,
                                    const float* __restrict__ asrc, const float* __restrict__ adst,
                                    const int* __restrict__ row_ptr, const int* __restrict__ col,
                                    const float* __restrict__ bias, float* __restrict__ out) {
    int node = blockIdx.x;
    int t = threadIdx.x;           // 0..63
    int head = t >> 5;
    float adn = adst[node * 2 + head];
    int beg = row_ptr[node], end = row_ptr[node + 1];
    // pass 1: max
    float m = -INFINITY;
    for (int i = beg; i < end; ++i) {
        float e = asrc[col[i] * 2 + head] + adn;
        e = (e >= 0.f) ? e : 0.2f * e;
        m = fmaxf(m, e);
    }
    // pass 2: sum + weighted gather
    float s = 0.f, ax = 0.f, ay = 0.f;
    for (int i = beg; i < end; ++i) {
        int sn = col[i];
        float e = asrc[sn * 2 + head] + adn;
        e = (e >= 0.f) ? e : 0.2f * e;
        float p = __expf(e - m);
        s += p;
        __hip_bfloat162 v = xl2[(size_t)sn * 64 + t];
        ax = fmaf(p, __bfloat162float(v.x), ax);
        ay = fmaf(p, __bfloat162float(v.y), ay);
    }
    float inv = 1.0f / (s + 1e-16f);
    float2 b2 = ((const float2*)bias)[t];
    float ox = fmaxf(ax * inv + b2.x, 0.f);
    float oy = fmaxf(ay * inv + b2.y, 0.f);
    ((float2*)out)[(size_t)node * 64 + t] = make_float2(ox, oy);
}

// final layer: HD=64, lane t = column t, head = t/32; mean heads + bias + log_softmax
__global__ void aggregate_final_bf16(const __hip_bfloat16* __restrict__ xl,
                                     const float* __restrict__ asrc, const float* __restrict__ adst,
                                     const int* __restrict__ row_ptr, const int* __restrict__ col,
                                     const float* __restrict__ bias, float* __restrict__ out) {
    int node = blockIdx.x;
    int t = threadIdx.x;  // 0..63
    int head = t >> 5;
    float adn = adst[node * 2 + head];
    int beg = row_ptr[node], end = row_ptr[node + 1];
    float m = -INFINITY;
    for (int i = beg; i < end; ++i) {
        float e = asrc[col[i] * 2 + head] + adn;
        e = (e >= 0.f) ? e : 0.2f * e;
        m = fmaxf(m, e);
    }
    float s = 0.f, acc = 0.f;
    for (int i = beg; i < end; ++i) {
        int sn = col[i];
        float e = asrc[sn * 2 + head] + adn;
        e = (e >= 0.f) ? e : 0.2f * e;
        float p = __expf(e - m);
        s += p;
        acc = fmaf(p, __bfloat162float(xl[(size_t)sn * 64 + t]), acc);
    }
    float o = acc / (s + 1e-16f);
    float other = __shfl_down(o, 32, 64);  // lane t<32 pulls head-1 partner
    if (t < 32) {
        float v = 0.5f * (o + other) + bias[t];
        float mx = v;
#pragma unroll
        for (int off = 16; off > 0; off >>= 1) mx = fmaxf(mx, __shfl_xor(mx, off, 32));
        float ex = __expf(v - mx);
        float sm = ex;
#pragma unroll
        for (int off = 16; off > 0; off >>= 1) sm += __shfl_xor(sm, off, 32);
        out[(size_t)node * 32 + t] = v - mx - logf(sm);
    }
}

// ---------------- launch ----------------

extern "C" void kernel_launch(void* const* d_in, const int* in_sizes, int n_in,
                              void* d_out, int out_size, void* d_ws, size_t ws_size,
                              hipStream_t stream) {
    const int N = N_NODES, E = N_EDGES;

    const float* x  = (const float*)d_in[0];
    const int*  ei  = (const int*)d_in[1];
    const float* W0 = (const float*)d_in[2];
    const float* as0 = (const float*)d_in[3];
    const float* ad0 = (const float*)d_in[4];
    const float* b0 = (const float*)d_in[5];
    const float* W1 = (const float*)d_in[6];
    const float* as1 = (const float*)d_in[7];
    const float* ad1 = (const float*)d_in[8];
    const float* b1 = (const float*)d_in[9];
    const float* W2 = (const float*)d_in[10];
    const float* as2 = (const float*)d_in[11];
    const float* ad2 = (const float*)d_in[12];
    const float* b2 = (const float*)d_in[13];
    const float* W3 = (const float*)d_in[14];
    const float* as3 = (const float*)d_in[15];
    const float* ad3 = (const float*)d_in[16];
    const float* b3 = (const float*)d_in[17];
    float* out = (float*)d_out;

    const int* srcv = ei;       // edge_index[0]
    const int* dstv = ei + E;   // edge_index[1]

    // carve workspace (256B aligned)
    char* p = (char*)d_ws;
    auto carve = [&](size_t bytes) -> void* {
        void* r = (void*)p;
        p += (bytes + 255) & ~(size_t)255;
        return r;
    };
    int* deg      = (int*)carve((size_t)N * 4);
    int* fill     = (int*)carve((size_t)N * 4);
    int* rp       = (int*)carve((size_t)(N + 1) * 4);
    int* col      = (int*)carve((size_t)E * 4);
    int* partials = (int*)carve((size_t)SCAN_B * 4);
    __hip_bfloat16* bufX = (__hip_bfloat16*)carve((size_t)N * 128 * 2);  // xl, bf16
    float* bufH   = (float*)carve((size_t)N * 128 * 4);                  // h, fp32
    float* asrc   = (float*)carve((size_t)N * 2 * 4);
    float* adst   = (float*)carve((size_t)N * 2 * 4);

    hipMemsetAsync(deg, 0, (size_t)N * 4, stream);
    hipMemsetAsync(fill, 0, (size_t)N * 4, stream);
    hipMemsetAsync(rp, 0, 4, stream);

    // CSR by destination
    hist_kernel<<<(E + 255) / 256, 256, 0, stream>>>(dstv, deg, E);
    int nb = (N + SCAN_B - 1) / SCAN_B;
    scan_block_kernel<<<nb, SCAN_B, 0, stream>>>(deg, rp + 1, partials, N);
    scan_partials_kernel<<<1, SCAN_B, 0, stream>>>(partials, nb);
    scan_add_kernel<<<nb, SCAN_B, 0, stream>>>(rp + 1, partials, N);
    scatter_kernel<<<(E + 255) / 256, 256, 0, stream>>>(srcv, dstv, rp, fill, col, E);

    constexpr int NPB = 16;  // nodes per block in gemm (N % NPB == 0)
    const __hip_bfloat162* bufX2 = (const __hip_bfloat162*)bufX;

    // layer 0
    gemm_alpha_kernel<128, 128, 64, NPB><<<N / NPB, 128, 0, stream>>>(x, W0, as0, ad0, bufX, asrc, adst);
    aggregate_relu_bf16<<<N, 64, 0, stream>>>(bufX2, asrc, adst, rp, col, b0, bufH);
    // layer 1
    gemm_alpha_kernel<128, 128, 64, NPB><<<N / NPB, 128, 0, stream>>>(bufH, W1, as1, ad1, bufX, asrc, adst);
    aggregate_relu_bf16<<<N, 64, 0, stream>>>(bufX2, asrc, adst, rp, col, b1, bufH);
    // layer 2
    gemm_alpha_kernel<128, 128, 64, NPB><<<N / NPB, 128, 0, stream>>>(bufH, W2, as2, ad2, bufX, asrc, adst);
    aggregate_relu_bf16<<<N, 64, 0, stream>>>(bufX2, asrc, adst, rp, col, b2, bufH);
    // layer 3: [N,128] @ W3[128,64] -> xl [N,2,32]; mean heads + bias + log_softmax
    gemm_alpha_kernel<128, 64, 32, NPB><<<N / NPB, 64, 0, stream>>>(bufH, W3, as3, ad3, bufX, asrc, adst);
    aggregate_final_bf16<<<N, 64, 0, stream>>>(bufX, asrc, adst, rp, col, b3, out);
}

// Round 4
// 781.998 us; speedup vs baseline: 1.6446x; 1.4692x over previous
//
#include <hip/hip_runtime.h>
#include <hip/hip_bf16.h>
#include <math.h>

#define N_NODES 100000
#define N_EDGES 1600000

constexpr int SCAN_B = 1024;

__device__ __forceinline__ unsigned short f2bf(float f) {
    unsigned int u = __float_as_uint(f);
    unsigned int r = (u + 0x7fff + ((u >> 16) & 1)) >> 16;  // RNE, finite inputs
    return (unsigned short)r;
}

// ---------------- CSR build ----------------

__global__ void hist_kernel(const int* __restrict__ dst, int* __restrict__ deg, int E) {
    int e = blockIdx.x * blockDim.x + threadIdx.x;
    if (e < E) atomicAdd(&deg[dst[e]], 1);
}

__global__ void scan_block_kernel(const int* __restrict__ in, int* __restrict__ out,
                                  int* __restrict__ partials, int n) {
    __shared__ int sh[SCAN_B];
    int gid = blockIdx.x * SCAN_B + threadIdx.x;
    int v = (gid < n) ? in[gid] : 0;
    sh[threadIdx.x] = v;
    __syncthreads();
    for (int off = 1; off < SCAN_B; off <<= 1) {
        int x = (threadIdx.x >= (unsigned)off) ? sh[threadIdx.x - off] : 0;
        __syncthreads();
        sh[threadIdx.x] += x;
        __syncthreads();
    }
    if (gid < n) out[gid] = sh[threadIdx.x];
    if (threadIdx.x == SCAN_B - 1) partials[blockIdx.x] = sh[SCAN_B - 1];
}

__global__ void scan_partials_kernel(int* partials, int nb) {
    __shared__ int sh[SCAN_B];
    int v = (threadIdx.x < (unsigned)nb) ? partials[threadIdx.x] : 0;
    sh[threadIdx.x] = v;
    __syncthreads();
    for (int off = 1; off < SCAN_B; off <<= 1) {
        int x = (threadIdx.x >= (unsigned)off) ? sh[threadIdx.x - off] : 0;
        __syncthreads();
        sh[threadIdx.x] += x;
        __syncthreads();
    }
    if (threadIdx.x < (unsigned)nb) partials[threadIdx.x] = sh[threadIdx.x] - v; // exclusive
}

__global__ void scan_add_kernel(int* out, const int* __restrict__ partials, int n) {
    int gid = blockIdx.x * SCAN_B + threadIdx.x;
    if (gid < n) out[gid] += partials[blockIdx.x];
}

__global__ void scatter_kernel(const int* __restrict__ src, const int* __restrict__ dst,
                               const int* __restrict__ row_ptr, int* __restrict__ fill,
                               int* __restrict__ col, int E) {
    int e = blockIdx.x * blockDim.x + threadIdx.x;
    if (e < E) {
        int d = dst[e];
        int pos = row_ptr[d] + atomicAdd(&fill[d], 1);
        col[pos] = src[e];
    }
}

// ---------------- per-layer GEMM + attention dots ----------------
// block = 64 threads (1 wave), NPB=16 nodes per block. Thread owns 4 output
// columns (float4 acc) for NPT nodes => 1 ds_read_b128 h-broadcast feeds
// 16 fma (LDS pipe ~= VALU pipe, overlapped).

template<int HD, int NPB>
__global__ void gemm_alpha_v2(const float* __restrict__ h, const float* __restrict__ W,
                              const float* __restrict__ a_s, const float* __restrict__ a_d,
                              __hip_bfloat16* __restrict__ xl, float* __restrict__ asrc,
                              float* __restrict__ adst) {
    constexpr int DIN = 128, C4 = DIN / 4;   // 32 float4 per h row
    constexpr int G = HD / 4;                // col groups (32 or 16); row = G uint2
    constexpr int NSPLIT = 64 / G;           // node splits per wave (2 or 4)
    constexpr int NPT = NPB / NSPLIT;        // nodes per thread (8 or 4)
    constexpr int HG = G / 2;                // lanes per head

    int node0 = blockIdx.x * NPB;
    int t = threadIdx.x;
    int cg = t % G, ns = t / G;

    __shared__ float4 hrow[NPB][C4];
    const float4* h4 = (const float4*)h;
    for (int idx = t; idx < NPB * C4; idx += 64) {
        int nn = idx / C4, kk = idx % C4;
        hrow[nn][kk] = h4[(size_t)(node0 + nn) * C4 + kk];
    }
    __syncthreads();

    const float4* W4 = (const float4*)W;
    float4 acc[NPT];
#pragma unroll
    for (int i = 0; i < NPT; ++i) acc[i] = make_float4(0.f, 0.f, 0.f, 0.f);

    for (int kc = 0; kc < C4; ++kc) {
        float4 w0 = W4[(size_t)(4 * kc + 0) * G + cg];
        float4 w1 = W4[(size_t)(4 * kc + 1) * G + cg];
        float4 w2 = W4[(size_t)(4 * kc + 2) * G + cg];
        float4 w3 = W4[(size_t)(4 * kc + 3) * G + cg];
#pragma unroll
        for (int nn = 0; nn < NPT; ++nn) {
            float4 hv = hrow[ns * NPT + nn][kc];
            acc[nn].x = fmaf(hv.w, w3.x, fmaf(hv.z, w2.x, fmaf(hv.y, w1.x, fmaf(hv.x, w0.x, acc[nn].x))));
            acc[nn].y = fmaf(hv.w, w3.y, fmaf(hv.z, w2.y, fmaf(hv.y, w1.y, fmaf(hv.x, w0.y, acc[nn].y))));
            acc[nn].z = fmaf(hv.w, w3.z, fmaf(hv.z, w2.z, fmaf(hv.y, w1.z, fmaf(hv.x, w0.z, acc[nn].z))));
            acc[nn].w = fmaf(hv.w, w3.w, fmaf(hv.z, w2.w, fmaf(hv.y, w1.w, fmaf(hv.x, w0.w, acc[nn].w))));
        }
    }

    float4 asv = ((const float4*)a_s)[cg];
    float4 adv = ((const float4*)a_d)[cg];
#pragma unroll
    for (int nn = 0; nn < NPT; ++nn) {
        int node = node0 + ns * NPT + nn;
        float4 a = acc[nn];
        uint2 u;
        u.x = (unsigned)f2bf(a.x) | ((unsigned)f2bf(a.y) << 16);
        u.y = (unsigned)f2bf(a.z) | ((unsigned)f2bf(a.w) << 16);
        ((uint2*)xl)[(size_t)node * G + cg] = u;   // row = G uint2 (FIX: was HD/8)
        float ps = a.x * asv.x + a.y * asv.y + a.z * asv.z + a.w * asv.w;
        float pd = a.x * adv.x + a.y * adv.y + a.z * adv.z + a.w * adv.w;
#pragma unroll
        for (int off = G / 4; off >= 1; off >>= 1) {
            ps += __shfl_xor(ps, off, 64);
            pd += __shfl_xor(pd, off, 64);
        }
        if ((cg & (HG - 1)) == 0) {
            int head = cg / HG;
            asrc[node * 2 + head] = ps;
            adst[node * 2 + head] = pd;
        }
    }
}

// ---------------- aggregation v3 ----------------
// one wave per destination node. Phase 1: lane-parallel max. Phase 2a:
// lane-parallel p=exp(e-m) staged in LDS (kills 32x-redundant scalar math).
// Phase 2b: broadcast-read gather, unrolled x4 for memory-level parallelism.

__global__ void aggregate_relu_v3(const __hip_bfloat162* __restrict__ xl2,
                                  const float2* __restrict__ a_src, const float2* __restrict__ a_dst,
                                  const int* __restrict__ rp, const int* __restrict__ col,
                                  const float* __restrict__ bias, float* __restrict__ out) {
    int node = blockIdx.x;
    int t = threadIdx.x;           // 0..63
    int head = t >> 5;
    int beg = rp[node], deg = rp[node + 1] - beg;
    float2 adn = a_dst[node];

    __shared__ int   snS[64];
    __shared__ float pS[2][64];

    // pass 1: lane-parallel max (both heads per lane)
    float m0 = -INFINITY, m1 = -INFINITY;
    for (int j = t; j < deg; j += 64) {
        float2 a = a_src[col[beg + j]];
        float e0 = a.x + adn.x; e0 = (e0 >= 0.f) ? e0 : 0.2f * e0;
        float e1 = a.y + adn.y; e1 = (e1 >= 0.f) ? e1 : 0.2f * e1;
        m0 = fmaxf(m0, e0); m1 = fmaxf(m1, e1);
    }
#pragma unroll
    for (int off = 32; off >= 1; off >>= 1) {
        m0 = fmaxf(m0, __shfl_xor(m0, off, 64));
        m1 = fmaxf(m1, __shfl_xor(m1, off, 64));
    }

    float s0 = 0.f, s1 = 0.f;
    float ax0 = 0.f, ay0 = 0.f, ax1 = 0.f, ay1 = 0.f;
    for (int c0 = 0; c0 < deg; c0 += 64) {
        int csz = min(64, deg - c0);
        if (t < csz) {
            int sn = col[beg + c0 + t];
            float2 a = a_src[sn];
            float e0 = a.x + adn.x; e0 = (e0 >= 0.f) ? e0 : 0.2f * e0;
            float e1 = a.y + adn.y; e1 = (e1 >= 0.f) ? e1 : 0.2f * e1;
            float p0 = __expf(e0 - m0), p1 = __expf(e1 - m1);
            snS[t] = sn; pS[0][t] = p0; pS[1][t] = p1;
            s0 += p0; s1 += p1;
        }
        __syncthreads();
        int j = 0;
        for (; j + 4 <= csz; j += 4) {
            int sna = snS[j], snb = snS[j + 1], snc = snS[j + 2], snd = snS[j + 3];
            float pa = pS[head][j], pb = pS[head][j + 1], pc = pS[head][j + 2], pd = pS[head][j + 3];
            __hip_bfloat162 va = xl2[(size_t)sna * 64 + t];
            __hip_bfloat162 vb = xl2[(size_t)snb * 64 + t];
            __hip_bfloat162 vc = xl2[(size_t)snc * 64 + t];
            __hip_bfloat162 vd = xl2[(size_t)snd * 64 + t];
            ax0 = fmaf(pa, __bfloat162float(va.x), ax0); ay0 = fmaf(pa, __bfloat162float(va.y), ay0);
            ax1 = fmaf(pb, __bfloat162float(vb.x), ax1); ay1 = fmaf(pb, __bfloat162float(vb.y), ay1);
            ax0 = fmaf(pc, __bfloat162float(vc.x), ax0); ay0 = fmaf(pc, __bfloat162float(vc.y), ay0);
            ax1 = fmaf(pd, __bfloat162float(vd.x), ax1); ay1 = fmaf(pd, __bfloat162float(vd.y), ay1);
        }
        for (; j < csz; ++j) {
            int sn = snS[j];
            float p = pS[head][j];
            __hip_bfloat162 v = xl2[(size_t)sn * 64 + t];
            ax0 = fmaf(p, __bfloat162float(v.x), ax0);
            ay0 = fmaf(p, __bfloat162float(v.y), ay0);
        }
        __syncthreads();
    }
#pragma unroll
    for (int off = 32; off >= 1; off >>= 1) {
        s0 += __shfl_xor(s0, off, 64);
        s1 += __shfl_xor(s1, off, 64);
    }
    float s = head ? s1 : s0;
    float inv = 1.0f / (s + 1e-16f);
    float2 b2 = ((const float2*)bias)[t];
    float ox = fmaxf(fmaf(ax0 + ax1, inv, b2.x), 0.f);
    float oy = fmaxf(fmaf(ay0 + ay1, inv, b2.y), 0.f);
    ((float2*)out)[(size_t)node * 64 + t] = make_float2(ox, oy);
}

// final layer: HD=64, lane t = one column; mean heads + bias + log_softmax
__global__ void aggregate_final_v3(const __hip_bfloat16* __restrict__ xl,
                                   const float2* __restrict__ a_src, const float2* __restrict__ a_dst,
                                   const int* __restrict__ rp, const int* __restrict__ col,
                                   const float* __restrict__ bias, float* __restrict__ out) {
    int node = blockIdx.x;
    int t = threadIdx.x;  // 0..63
    int head = t >> 5;
    int beg = rp[node], deg = rp[node + 1] - beg;
    float2 adn = a_dst[node];

    __shared__ int   snS[64];
    __shared__ float pS[2][64];

    float m0 = -INFINITY, m1 = -INFINITY;
    for (int j = t; j < deg; j += 64) {
        float2 a = a_src[col[beg + j]];
        float e0 = a.x + adn.x; e0 = (e0 >= 0.f) ? e0 : 0.2f * e0;
        float e1 = a.y + adn.y; e1 = (e1 >= 0.f) ? e1 : 0.2f * e1;
        m0 = fmaxf(m0, e0); m1 = fmaxf(m1, e1);
    }
#pragma unroll
    for (int off = 32; off >= 1; off >>= 1) {
        m0 = fmaxf(m0, __shfl_xor(m0, off, 64));
        m1 = fmaxf(m1, __shfl_xor(m1, off, 64));
    }

    float s0 = 0.f, s1 = 0.f, acc0 = 0.f, acc1 = 0.f;
    for (int c0 = 0; c0 < deg; c0 += 64) {
        int csz = min(64, deg - c0);
        if (t < csz) {
            int sn = col[beg + c0 + t];
            float2 a = a_src[sn];
            float e0 = a.x + adn.x; e0 = (e0 >= 0.f) ? e0 : 0.2f * e0;
            float e1 = a.y + adn.y; e1 = (e1 >= 0.f) ? e1 : 0.2f * e1;
            float p0 = __expf(e0 - m0), p1 = __expf(e1 - m1);
            snS[t] = sn; pS[0][t] = p0; pS[1][t] = p1;
            s0 += p0; s1 += p1;
        }
        __syncthreads();
        int j = 0;
        for (; j + 4 <= csz; j += 4) {
            int sna = snS[j], snb = snS[j + 1], snc = snS[j + 2], snd = snS[j + 3];
            float pa = pS[head][j], pb = pS[head][j + 1], pc = pS[head][j + 2], pd = pS[head][j + 3];
            float va = __bfloat162float(xl[(size_t)sna * 64 + t]);
            float vb = __bfloat162float(xl[(size_t)snb * 64 + t]);
            float vc = __bfloat162float(xl[(size_t)snc * 64 + t]);
            float vd = __bfloat162float(xl[(size_t)snd * 64 + t]);
            acc0 = fmaf(pa, va, acc0); acc1 = fmaf(pb, vb, acc1);
            acc0 = fmaf(pc, vc, acc0); acc1 = fmaf(pd, vd, acc1);
        }
        for (; j < csz; ++j) {
            acc0 = fmaf(pS[head][j], __bfloat162float(xl[(size_t)snS[j] * 64 + t]), acc0);
        }
        __syncthreads();
    }
#pragma unroll
    for (int off = 32; off >= 1; off >>= 1) {
        s0 += __shfl_xor(s0, off, 64);
        s1 += __shfl_xor(s1, off, 64);
    }
    float s = head ? s1 : s0;
    float o = (acc0 + acc1) / (s + 1e-16f);
    float other = __shfl_down(o, 32, 64);
    if (t < 32) {
        float v = 0.5f * (o + other) + bias[t];
        float mx = v;
#pragma unroll
        for (int off = 16; off >= 1; off >>= 1) mx = fmaxf(mx, __shfl_xor(mx, off, 32));
        float ex = __expf(v - mx);
        float sm = ex;
#pragma unroll
        for (int off = 16; off >= 1; off >>= 1) sm += __shfl_xor(sm, off, 32);
        out[(size_t)node * 32 + t] = v - mx - logf(sm);
    }
}

// ---------------- launch ----------------

extern "C" void kernel_launch(void* const* d_in, const int* in_sizes, int n_in,
                              void* d_out, int out_size, void* d_ws, size_t ws_size,
                              hipStream_t stream) {
    const int N = N_NODES, E = N_EDGES;

    const float* x  = (const float*)d_in[0];
    const int*  ei  = (const int*)d_in[1];
    const float* W0 = (const float*)d_in[2];
    const float* as0 = (const float*)d_in[3];
    const float* ad0 = (const float*)d_in[4];
    const float* b0 = (const float*)d_in[5];
    const float* W1 = (const float*)d_in[6];
    const float* as1 = (const float*)d_in[7];
    const float* ad1 = (const float*)d_in[8];
    const float* b1 = (const float*)d_in[9];
    const float* W2 = (const float*)d_in[10];
    const float* as2 = (const float*)d_in[11];
    const float* ad2 = (const float*)d_in[12];
    const float* b2 = (const float*)d_in[13];
    const float* W3 = (const float*)d_in[14];
    const float* as3 = (const float*)d_in[15];
    const float* ad3 = (const float*)d_in[16];
    const float* b3 = (const float*)d_in[17];
    float* out = (float*)d_out;

    const int* srcv = ei;       // edge_index[0]
    const int* dstv = ei + E;   // edge_index[1]

    char* p = (char*)d_ws;
    auto carve = [&](size_t bytes) -> void* {
        void* r = (void*)p;
        p += (bytes + 255) & ~(size_t)255;
        return r;
    };
    int* deg      = (int*)carve((size_t)N * 4);
    int* fill     = (int*)carve((size_t)N * 4);
    int* rp       = (int*)carve((size_t)(N + 1) * 4);
    int* col      = (int*)carve((size_t)E * 4);
    int* partials = (int*)carve((size_t)SCAN_B * 4);
    __hip_bfloat16* bufX = (__hip_bfloat16*)carve((size_t)N * 128 * 2);  // xl, bf16
    float* bufH   = (float*)carve((size_t)N * 128 * 4);                  // h, fp32
    float* asrc   = (float*)carve((size_t)N * 2 * 4);
    float* adst   = (float*)carve((size_t)N * 2 * 4);

    hipMemsetAsync(deg, 0, (size_t)N * 4, stream);
    hipMemsetAsync(fill, 0, (size_t)N * 4, stream);
    hipMemsetAsync(rp, 0, 4, stream);

    hist_kernel<<<(E + 255) / 256, 256, 0, stream>>>(dstv, deg, E);
    int nb = (N + SCAN_B - 1) / SCAN_B;
    scan_block_kernel<<<nb, SCAN_B, 0, stream>>>(deg, rp + 1, partials, N);
    scan_partials_kernel<<<1, SCAN_B, 0, stream>>>(partials, nb);
    scan_add_kernel<<<nb, SCAN_B, 0, stream>>>(rp + 1, partials, N);
    scatter_kernel<<<(E + 255) / 256, 256, 0, stream>>>(srcv, dstv, rp, fill, col, E);

    constexpr int NPB = 16;  // 100000 % 16 == 0
    const __hip_bfloat162* bufX2 = (const __hip_bfloat162*)bufX;
    const float2* asrc2 = (const float2*)asrc;
    const float2* adst2 = (const float2*)adst;

    // layer 0
    gemm_alpha_v2<128, NPB><<<N / NPB, 64, 0, stream>>>(x, W0, as0, ad0, bufX, asrc, adst);
    aggregate_relu_v3<<<N, 64, 0, stream>>>(bufX2, asrc2, adst2, rp, col, b0, bufH);
    // layer 1
    gemm_alpha_v2<128, NPB><<<N / NPB, 64, 0, stream>>>(bufH, W1, as1, ad1, bufX, asrc, adst);
    aggregate_relu_v3<<<N, 64, 0, stream>>>(bufX2, asrc2, adst2, rp, col, b1, bufH);
    // layer 2
    gemm_alpha_v2<128, NPB><<<N / NPB, 64, 0, stream>>>(bufH, W2, as2, ad2, bufX, asrc, adst);
    aggregate_relu_v3<<<N, 64, 0, stream>>>(bufX2, asrc2, adst2, rp, col, b2, bufH);
    // layer 3
    gemm_alpha_v2<64, NPB><<<N / NPB, 64, 0, stream>>>(bufH, W3, as3, ad3, bufX, asrc, adst);
    aggregate_final_v3<<<N, 64, 0, stream>>>(bufX, asrc2, adst2, rp, col, b3, out);
}

// Round 5
// 644.242 us; speedup vs baseline: 1.9963x; 1.2138x over previous
//
#include <hip/hip_runtime.h>
#include <hip/hip_bf16.h>
#include <math.h>

#define N_NODES 100000
#define N_EDGES 1600000

constexpr int SCAN_B = 1024;

// bucketed CSR build params
constexpr int BSHIFT = 9, BMASK = 511;           // 512 nodes per bucket
constexpr int NBUCKET = (N_NODES + 511) / 512;   // 196
constexpr int BCAP = 16384;                      // entries per bucket (mean 8192, +45 sigma)
constexpr int CAPB = 12288;                      // LDS col staging entries
constexpr int EPT = 16, BIN_T = 256, BIN_CHUNK = BIN_T * EPT;  // 4096 edges/block

__device__ __forceinline__ unsigned short f2bf(float f) {
    unsigned int u = __float_as_uint(f);
    unsigned int r = (u + 0x7fff + ((u >> 16) & 1)) >> 16;  // RNE, finite inputs
    return (unsigned short)r;
}

// ---------------- CSR build (bucketed, low write-amplification) ----------------

// Phase A: bin edges into NBUCKET buckets of 512 dst nodes; entry = (src<<9)|dstLocal.
__global__ __launch_bounds__(BIN_T) void bin_kernel(const int* __restrict__ src,
                                                    const int* __restrict__ dst,
                                                    int* __restrict__ bcnt,
                                                    unsigned int* __restrict__ bstore, int E) {
    __shared__ int cnt[NBUCKET];
    __shared__ int base[NBUCKET];
    int t = threadIdx.x;
    for (int i = t; i < NBUCKET; i += BIN_T) cnt[i] = 0;
    __syncthreads();
    int e0 = blockIdx.x * BIN_CHUNK;
    int ssrc[EPT], sdst[EPT];
#pragma unroll
    for (int k = 0; k < EPT; ++k) {
        int e = e0 + t + k * BIN_T;
        if (e < E) {
            ssrc[k] = src[e];
            sdst[k] = dst[e];
            atomicAdd(&cnt[sdst[k] >> BSHIFT], 1);
        } else {
            sdst[k] = -1;
        }
    }
    __syncthreads();
    for (int i = t; i < NBUCKET; i += BIN_T) {
        base[i] = atomicAdd(&bcnt[i], cnt[i]);
        cnt[i] = 0;
    }
    __syncthreads();
#pragma unroll
    for (int k = 0; k < EPT; ++k) {
        if (sdst[k] >= 0) {
            int b = sdst[k] >> BSHIFT;
            int off = base[b] + atomicAdd(&cnt[b], 1);
            if (off < BCAP)
                bstore[(size_t)b * BCAP + off] =
                    ((unsigned)ssrc[k] << BSHIFT) | (unsigned)(sdst[k] & BMASK);
        }
    }
}

// Degrees from bucket entries: LDS hist + coalesced write (covers all nodes, incl. zeros).
__global__ __launch_bounds__(256) void deg_from_buckets(const int* __restrict__ bcnt,
                                                        const unsigned int* __restrict__ bstore,
                                                        int* __restrict__ deg, int N) {
    __shared__ int dcnt[512];
    int b = blockIdx.x, t = threadIdx.x;
    for (int i = t; i < 512; i += 256) dcnt[i] = 0;
    __syncthreads();
    int cnt = min(bcnt[b], BCAP);
    for (int i = t; i < cnt; i += 256)
        atomicAdd(&dcnt[bstore[(size_t)b * BCAP + i] & BMASK], 1);
    __syncthreads();
    int nodeBase = b << BSHIFT;
    for (int i = t; i < 512; i += 256)
        if (nodeBase + i < N) deg[nodeBase + i] = dcnt[i];
}

__global__ void scan_block_kernel(const int* __restrict__ in, int* __restrict__ out,
                                  int* __restrict__ partials, int n) {
    __shared__ int sh[SCAN_B];
    int gid = blockIdx.x * SCAN_B + threadIdx.x;
    int v = (gid < n) ? in[gid] : 0;
    sh[threadIdx.x] = v;
    __syncthreads();
    for (int off = 1; off < SCAN_B; off <<= 1) {
        int x = (threadIdx.x >= (unsigned)off) ? sh[threadIdx.x - off] : 0;
        __syncthreads();
        sh[threadIdx.x] += x;
        __syncthreads();
    }
    if (gid < n) out[gid] = sh[threadIdx.x];
    if (threadIdx.x == SCAN_B - 1) partials[blockIdx.x] = sh[SCAN_B - 1];
}

__global__ void scan_partials_kernel(int* partials, int nb) {
    __shared__ int sh[SCAN_B];
    int v = (threadIdx.x < (unsigned)nb) ? partials[threadIdx.x] : 0;
    sh[threadIdx.x] = v;
    __syncthreads();
    for (int off = 1; off < SCAN_B; off <<= 1) {
        int x = (threadIdx.x >= (unsigned)off) ? sh[threadIdx.x - off] : 0;
        __syncthreads();
        sh[threadIdx.x] += x;
        __syncthreads();
    }
    if (threadIdx.x < (unsigned)nb) partials[threadIdx.x] = sh[threadIdx.x] - v; // exclusive
}

__global__ void scan_add_kernel(int* out, const int* __restrict__ partials, int n) {
    int gid = blockIdx.x * SCAN_B + threadIdx.x;
    if (gid < n) out[gid] += partials[blockIdx.x];
}

// Phase B: per bucket, stage the whole col segment in LDS, then write coalesced.
__global__ __launch_bounds__(256) void build_col_kernel(const int* __restrict__ rp,
                                                        const int* __restrict__ bcnt,
                                                        const unsigned int* __restrict__ bstore,
                                                        int* __restrict__ col, int N) {
    __shared__ int colStage[CAPB];
    __shared__ int rpL[513];
    __shared__ int fillL[512];
    int b = blockIdx.x, t = threadIdx.x;
    int nodeBase = b << BSHIFT;
    int nNodes = min(512, N - nodeBase);
    for (int i = t; i <= nNodes; i += 256) rpL[i] = rp[nodeBase + i];
    for (int i = t; i < nNodes; i += 256) fillL[i] = 0;
    __syncthreads();
    int segBase = rpL[0];
    int segLen = rpL[nNodes] - segBase;
    int cnt = min(bcnt[b], BCAP);
    for (int i = t; i < cnt; i += 256) {
        unsigned e = bstore[(size_t)b * BCAP + i];
        int dl = e & BMASK;
        int sv = (int)(e >> BSHIFT);
        int pos = (rpL[dl] - segBase) + atomicAdd(&fillL[dl], 1);
        if (pos < CAPB) colStage[pos] = sv;
        else col[segBase + pos] = sv;   // overflow fallback (statistically impossible)
    }
    __syncthreads();
    int lim = min(segLen, CAPB);
    for (int i = t; i < lim; i += 256) col[segBase + i] = colStage[i];
}

// ---------------- per-layer GEMM + attention dots ----------------

template<int HD, int NPB>
__global__ void gemm_alpha_v2(const float* __restrict__ h, const float* __restrict__ W,
                              const float* __restrict__ a_s, const float* __restrict__ a_d,
                              __hip_bfloat16* __restrict__ xl, float* __restrict__ asrc,
                              float* __restrict__ adst) {
    constexpr int DIN = 128, C4 = DIN / 4;   // 32 float4 per h row
    constexpr int G = HD / 4;                // col groups (32 or 16); row = G uint2
    constexpr int NSPLIT = 64 / G;           // node splits per wave (2 or 4)
    constexpr int NPT = NPB / NSPLIT;        // nodes per thread (8 or 4)
    constexpr int HG = G / 2;                // lanes per head

    int node0 = blockIdx.x * NPB;
    int t = threadIdx.x;
    int cg = t % G, ns = t / G;

    __shared__ float4 hrow[NPB][C4];
    const float4* h4 = (const float4*)h;
    for (int idx = t; idx < NPB * C4; idx += 64) {
        int nn = idx / C4, kk = idx % C4;
        hrow[nn][kk] = h4[(size_t)(node0 + nn) * C4 + kk];
    }
    __syncthreads();

    const float4* W4 = (const float4*)W;
    float4 acc[NPT];
#pragma unroll
    for (int i = 0; i < NPT; ++i) acc[i] = make_float4(0.f, 0.f, 0.f, 0.f);

    for (int kc = 0; kc < C4; ++kc) {
        float4 w0 = W4[(size_t)(4 * kc + 0) * G + cg];
        float4 w1 = W4[(size_t)(4 * kc + 1) * G + cg];
        float4 w2 = W4[(size_t)(4 * kc + 2) * G + cg];
        float4 w3 = W4[(size_t)(4 * kc + 3) * G + cg];
#pragma unroll
        for (int nn = 0; nn < NPT; ++nn) {
            float4 hv = hrow[ns * NPT + nn][kc];
            acc[nn].x = fmaf(hv.w, w3.x, fmaf(hv.z, w2.x, fmaf(hv.y, w1.x, fmaf(hv.x, w0.x, acc[nn].x))));
            acc[nn].y = fmaf(hv.w, w3.y, fmaf(hv.z, w2.y, fmaf(hv.y, w1.y, fmaf(hv.x, w0.y, acc[nn].y))));
            acc[nn].z = fmaf(hv.w, w3.z, fmaf(hv.z, w2.z, fmaf(hv.y, w1.z, fmaf(hv.x, w0.z, acc[nn].z))));
            acc[nn].w = fmaf(hv.w, w3.w, fmaf(hv.z, w2.w, fmaf(hv.y, w1.w, fmaf(hv.x, w0.w, acc[nn].w))));
        }
    }

    float4 asv = ((const float4*)a_s)[cg];
    float4 adv = ((const float4*)a_d)[cg];
#pragma unroll
    for (int nn = 0; nn < NPT; ++nn) {
        int node = node0 + ns * NPT + nn;
        float4 a = acc[nn];
        uint2 u;
        u.x = (unsigned)f2bf(a.x) | ((unsigned)f2bf(a.y) << 16);
        u.y = (unsigned)f2bf(a.z) | ((unsigned)f2bf(a.w) << 16);
        ((uint2*)xl)[(size_t)node * G + cg] = u;   // row = G uint2
        float ps = a.x * asv.x + a.y * asv.y + a.z * asv.z + a.w * asv.w;
        float pd = a.x * adv.x + a.y * adv.y + a.z * adv.z + a.w * adv.w;
#pragma unroll
        for (int off = G / 4; off >= 1; off >>= 1) {
            ps += __shfl_xor(ps, off, 64);
            pd += __shfl_xor(pd, off, 64);
        }
        if ((cg & (HG - 1)) == 0) {
            int head = cg / HG;
            asrc[node * 2 + head] = ps;
            adst[node * 2 + head] = pd;
        }
    }
}

// ---------------- aggregation v4 ----------------
// one wave per destination node; fast path (deg<=64): single col/a_src gather,
// gather loop x8 with 4 accumulator pairs for MLP.

__global__ void aggregate_relu_v4(const __hip_bfloat162* __restrict__ xl2,
                                  const float2* __restrict__ a_src, const float2* __restrict__ a_dst,
                                  const int* __restrict__ rp, const int* __restrict__ col,
                                  const float* __restrict__ bias, float* __restrict__ out) {
    int node = blockIdx.x;
    int t = threadIdx.x;           // 0..63
    int head = t >> 5;
    int beg = rp[node], deg = rp[node + 1] - beg;
    float2 adn = a_dst[node];

    __shared__ int   snS[64];
    __shared__ float pS[2][64];

    float s0 = 0.f, s1 = 0.f;
    float ax0 = 0.f, ay0 = 0.f, ax1 = 0.f, ay1 = 0.f;
    float ax2 = 0.f, ay2 = 0.f, ax3 = 0.f, ay3 = 0.f;

    if (deg <= 64) {
        // ---- fast path: one gather of col/a_src total ----
        float e0 = -INFINITY, e1 = -INFINITY;
        if (t < deg) {
            int sn = col[beg + t];
            snS[t] = sn;
            float2 a = a_src[sn];
            e0 = a.x + adn.x; e0 = (e0 >= 0.f) ? e0 : 0.2f * e0;
            e1 = a.y + adn.y; e1 = (e1 >= 0.f) ? e1 : 0.2f * e1;
        }
        float m0 = e0, m1 = e1;
#pragma unroll
        for (int off = 32; off >= 1; off >>= 1) {
            m0 = fmaxf(m0, __shfl_xor(m0, off, 64));
            m1 = fmaxf(m1, __shfl_xor(m1, off, 64));
        }
        if (t < deg) {
            float p0 = __expf(e0 - m0), p1 = __expf(e1 - m1);
            pS[0][t] = p0; pS[1][t] = p1;
            s0 = p0; s1 = p1;
        }
        __syncthreads();
        int j = 0;
        for (; j + 8 <= deg; j += 8) {
            int sa = snS[j+0], sb = snS[j+1], sc = snS[j+2], sd = snS[j+3];
            int se = snS[j+4], sf = snS[j+5], sg = snS[j+6], sh = snS[j+7];
            float pa = pS[head][j+0], pb = pS[head][j+1], pc = pS[head][j+2], pd = pS[head][j+3];
            float pe = pS[head][j+4], pf = pS[head][j+5], pg = pS[head][j+6], ph = pS[head][j+7];
            __hip_bfloat162 va = xl2[(size_t)sa * 64 + t];
            __hip_bfloat162 vb = xl2[(size_t)sb * 64 + t];
            __hip_bfloat162 vc = xl2[(size_t)sc * 64 + t];
            __hip_bfloat162 vd = xl2[(size_t)sd * 64 + t];
            __hip_bfloat162 ve = xl2[(size_t)se * 64 + t];
            __hip_bfloat162 vf = xl2[(size_t)sf * 64 + t];
            __hip_bfloat162 vg = xl2[(size_t)sg * 64 + t];
            __hip_bfloat162 vh = xl2[(size_t)sh * 64 + t];
            ax0 = fmaf(pa, __bfloat162float(va.x), ax0); ay0 = fmaf(pa, __bfloat162float(va.y), ay0);
            ax1 = fmaf(pb, __bfloat162float(vb.x), ax1); ay1 = fmaf(pb, __bfloat162float(vb.y), ay1);
            ax2 = fmaf(pc, __bfloat162float(vc.x), ax2); ay2 = fmaf(pc, __bfloat162float(vc.y), ay2);
            ax3 = fmaf(pd, __bfloat162float(vd.x), ax3); ay3 = fmaf(pd, __bfloat162float(vd.y), ay3);
            ax0 = fmaf(pe, __bfloat162float(ve.x), ax0); ay0 = fmaf(pe, __bfloat162float(ve.y), ay0);
            ax1 = fmaf(pf, __bfloat162float(vf.x), ax1); ay1 = fmaf(pf, __bfloat162float(vf.y), ay1);
            ax2 = fmaf(pg, __bfloat162float(vg.x), ax2); ay2 = fmaf(pg, __bfloat162float(vg.y), ay2);
            ax3 = fmaf(ph, __bfloat162float(vh.x), ax3); ay3 = fmaf(ph, __bfloat162float(vh.y), ay3);
        }
        for (; j < deg; ++j) {
            int sn = snS[j];
            float p = pS[head][j];
            __hip_bfloat162 v = xl2[(size_t)sn * 64 + t];
            ax0 = fmaf(p, __bfloat162float(v.x), ax0);
            ay0 = fmaf(p, __bfloat162float(v.y), ay0);
        }
    } else {
        // ---- generic chunked path (statistically never taken at deg~16) ----
        float m0 = -INFINITY, m1 = -INFINITY;
        for (int j = t; j < deg; j += 64) {
            float2 a = a_src[col[beg + j]];
            float e0 = a.x + adn.x; e0 = (e0 >= 0.f) ? e0 : 0.2f * e0;
            float e1 = a.y + adn.y; e1 = (e1 >= 0.f) ? e1 : 0.2f * e1;
            m0 = fmaxf(m0, e0); m1 = fmaxf(m1, e1);
        }
#pragma unroll
        for (int off = 32; off >= 1; off >>= 1) {
            m0 = fmaxf(m0, __shfl_xor(m0, off, 64));
            m1 = fmaxf(m1, __shfl_xor(m1, off, 64));
        }
        for (int c0 = 0; c0 < deg; c0 += 64) {
            int csz = min(64, deg - c0);
            if (t < csz) {
                int sn = col[beg + c0 + t];
                float2 a = a_src[sn];
                float e0 = a.x + adn.x; e0 = (e0 >= 0.f) ? e0 : 0.2f * e0;
                float e1 = a.y + adn.y; e1 = (e1 >= 0.f) ? e1 : 0.2f * e1;
                float p0 = __expf(e0 - m0), p1 = __expf(e1 - m1);
                snS[t] = sn; pS[0][t] = p0; pS[1][t] = p1;
                s0 += p0; s1 += p1;
            }
            __syncthreads();
            for (int j = 0; j < csz; ++j) {
                int sn = snS[j];
                float p = pS[head][j];
                __hip_bfloat162 v = xl2[(size_t)sn * 64 + t];
                ax0 = fmaf(p, __bfloat162float(v.x), ax0);
                ay0 = fmaf(p, __bfloat162float(v.y), ay0);
            }
            __syncthreads();
        }
    }
#pragma unroll
    for (int off = 32; off >= 1; off >>= 1) {
        s0 += __shfl_xor(s0, off, 64);
        s1 += __shfl_xor(s1, off, 64);
    }
    float s = head ? s1 : s0;
    float inv = 1.0f / (s + 1e-16f);
    float2 b2 = ((const float2*)bias)[t];
    float ox = fmaxf(fmaf(ax0 + ax1 + ax2 + ax3, inv, b2.x), 0.f);
    float oy = fmaxf(fmaf(ay0 + ay1 + ay2 + ay3, inv, b2.y), 0.f);
    ((float2*)out)[(size_t)node * 64 + t] = make_float2(ox, oy);
}

// final layer: HD=64, lane t = one column; mean heads + bias + log_softmax
__global__ void aggregate_final_v4(const __hip_bfloat16* __restrict__ xl,
                                   const float2* __restrict__ a_src, const float2* __restrict__ a_dst,
                                   const int* __restrict__ rp, const int* __restrict__ col,
                                   const float* __restrict__ bias, float* __restrict__ out) {
    int node = blockIdx.x;
    int t = threadIdx.x;  // 0..63
    int head = t >> 5;
    int beg = rp[node], deg = rp[node + 1] - beg;
    float2 adn = a_dst[node];

    __shared__ int   snS[64];
    __shared__ float pS[2][64];

    float s0 = 0.f, s1 = 0.f;
    float a0 = 0.f, a1 = 0.f, a2 = 0.f, a3 = 0.f;

    if (deg <= 64) {
        float e0 = -INFINITY, e1 = -INFINITY;
        if (t < deg) {
            int sn = col[beg + t];
            snS[t] = sn;
            float2 a = a_src[sn];
            e0 = a.x + adn.x; e0 = (e0 >= 0.f) ? e0 : 0.2f * e0;
            e1 = a.y + adn.y; e1 = (e1 >= 0.f) ? e1 : 0.2f * e1;
        }
        float m0 = e0, m1 = e1;
#pragma unroll
        for (int off = 32; off >= 1; off >>= 1) {
            m0 = fmaxf(m0, __shfl_xor(m0, off, 64));
            m1 = fmaxf(m1, __shfl_xor(m1, off, 64));
        }
        if (t < deg) {
            float p0 = __expf(e0 - m0), p1 = __expf(e1 - m1);
            pS[0][t] = p0; pS[1][t] = p1;
            s0 = p0; s1 = p1;
        }
        __syncthreads();
        int j = 0;
        for (; j + 8 <= deg; j += 8) {
            int sa = snS[j+0], sb = snS[j+1], sc = snS[j+2], sd = snS[j+3];
            int se = snS[j+4], sf = snS[j+5], sg = snS[j+6], sh = snS[j+7];
            float pa = pS[head][j+0], pb = pS[head][j+1], pc = pS[head][j+2], pd = pS[head][j+3];
            float pe = pS[head][j+4], pf = pS[head][j+5], pg = pS[head][j+6], ph = pS[head][j+7];
            float va = __bfloat162float(xl[(size_t)sa * 64 + t]);
            float vb = __bfloat162float(xl[(size_t)sb * 64 + t]);
            float vc = __bfloat162float(xl[(size_t)sc * 64 + t]);
            float vd = __bfloat162float(xl[(size_t)sd * 64 + t]);
            float ve = __bfloat162float(xl[(size_t)se * 64 + t]);
            float vf = __bfloat162float(xl[(size_t)sf * 64 + t]);
            float vg = __bfloat162float(xl[(size_t)sg * 64 + t]);
            float vh = __bfloat162float(xl[(size_t)sh * 64 + t]);
            a0 = fmaf(pa, va, a0); a1 = fmaf(pb, vb, a1);
            a2 = fmaf(pc, vc, a2); a3 = fmaf(pd, vd, a3);
            a0 = fmaf(pe, ve, a0); a1 = fmaf(pf, vf, a1);
            a2 = fmaf(pg, vg, a2); a3 = fmaf(ph, vh, a3);
        }
        for (; j < deg; ++j) {
            a0 = fmaf(pS[head][j], __bfloat162float(xl[(size_t)snS[j] * 64 + t]), a0);
        }
    } else {
        float m0 = -INFINITY, m1 = -INFINITY;
        for (int j = t; j < deg; j += 64) {
            float2 a = a_src[col[beg + j]];
            float e0 = a.x + adn.x; e0 = (e0 >= 0.f) ? e0 : 0.2f * e0;
            float e1 = a.y + adn.y; e1 = (e1 >= 0.f) ? e1 : 0.2f * e1;
            m0 = fmaxf(m0, e0); m1 = fmaxf(m1, e1);
        }
#pragma unroll
        for (int off = 32; off >= 1; off >>= 1) {
            m0 = fmaxf(m0, __shfl_xor(m0, off, 64));
            m1 = fmaxf(m1, __shfl_xor(m1, off, 64));
        }
        for (int c0 = 0; c0 < deg; c0 += 64) {
            int csz = min(64, deg - c0);
            if (t < csz) {
                int sn = col[beg + c0 + t];
                float2 a = a_src[sn];
                float e0 = a.x + adn.x; e0 = (e0 >= 0.f) ? e0 : 0.2f * e0;
                float e1 = a.y + adn.y; e1 = (e1 >= 0.f) ? e1 : 0.2f * e1;
                float p0 = __expf(e0 - m0), p1 = __expf(e1 - m1);
                snS[t] = sn; pS[0][t] = p0; pS[1][t] = p1;
                s0 += p0; s1 += p1;
            }
            __syncthreads();
            for (int j = 0; j < csz; ++j) {
                a0 = fmaf(pS[head][j], __bfloat162float(xl[(size_t)snS[j] * 64 + t]), a0);
            }
            __syncthreads();
        }
    }
#pragma unroll
    for (int off = 32; off >= 1; off >>= 1) {
        s0 += __shfl_xor(s0, off, 64);
        s1 += __shfl_xor(s1, off, 64);
    }
    float s = head ? s1 : s0;
    float o = (a0 + a1 + a2 + a3) / (s + 1e-16f);
    float other = __shfl_down(o, 32, 64);
    if (t < 32) {
        float v = 0.5f * (o + other) + bias[t];
        float mx = v;
#pragma unroll
        for (int off = 16; off >= 1; off >>= 1) mx = fmaxf(mx, __shfl_xor(mx, off, 32));
        float ex = __expf(v - mx);
        float sm = ex;
#pragma unroll
        for (int off = 16; off >= 1; off >>= 1) sm += __shfl_xor(sm, off, 32);
        out[(size_t)node * 32 + t] = v - mx - logf(sm);
    }
}

// ---------------- launch ----------------

extern "C" void kernel_launch(void* const* d_in, const int* in_sizes, int n_in,
                              void* d_out, int out_size, void* d_ws, size_t ws_size,
                              hipStream_t stream) {
    const int N = N_NODES, E = N_EDGES;

    const float* x  = (const float*)d_in[0];
    const int*  ei  = (const int*)d_in[1];
    const float* W0 = (const float*)d_in[2];
    const float* as0 = (const float*)d_in[3];
    const float* ad0 = (const float*)d_in[4];
    const float* b0 = (const float*)d_in[5];
    const float* W1 = (const float*)d_in[6];
    const float* as1 = (const float*)d_in[7];
    const float* ad1 = (const float*)d_in[8];
    const float* b1 = (const float*)d_in[9];
    const float* W2 = (const float*)d_in[10];
    const float* as2 = (const float*)d_in[11];
    const float* ad2 = (const float*)d_in[12];
    const float* b2 = (const float*)d_in[13];
    const float* W3 = (const float*)d_in[14];
    const float* as3 = (const float*)d_in[15];
    const float* ad3 = (const float*)d_in[16];
    const float* b3 = (const float*)d_in[17];
    float* out = (float*)d_out;

    const int* srcv = ei;       // edge_index[0]
    const int* dstv = ei + E;   // edge_index[1]

    char* p = (char*)d_ws;
    auto carve = [&](size_t bytes) -> void* {
        void* r = (void*)p;
        p += (bytes + 255) & ~(size_t)255;
        return r;
    };
    int* deg      = (int*)carve((size_t)N * 4);
    int* rp       = (int*)carve((size_t)(N + 1) * 4);
    int* col      = (int*)carve((size_t)E * 4);
    int* partials = (int*)carve((size_t)SCAN_B * 4);
    int* bcnt     = (int*)carve((size_t)NBUCKET * 4);
    unsigned int* bstore = (unsigned int*)carve((size_t)NBUCKET * BCAP * 4);
    __hip_bfloat16* bufX = (__hip_bfloat16*)carve((size_t)N * 128 * 2);  // xl, bf16
    float* bufH   = (float*)carve((size_t)N * 128 * 4);                  // h, fp32
    float* asrc   = (float*)carve((size_t)N * 2 * 4);
    float* adst   = (float*)carve((size_t)N * 2 * 4);

    hipMemsetAsync(bcnt, 0, (size_t)NBUCKET * 4, stream);
    hipMemsetAsync(rp, 0, 4, stream);

    // bucketed CSR build
    bin_kernel<<<(E + BIN_CHUNK - 1) / BIN_CHUNK, BIN_T, 0, stream>>>(srcv, dstv, bcnt, bstore, E);
    deg_from_buckets<<<NBUCKET, 256, 0, stream>>>(bcnt, bstore, deg, N);
    int nb = (N + SCAN_B - 1) / SCAN_B;
    scan_block_kernel<<<nb, SCAN_B, 0, stream>>>(deg, rp + 1, partials, N);
    scan_partials_kernel<<<1, SCAN_B, 0, stream>>>(partials, nb);
    scan_add_kernel<<<nb, SCAN_B, 0, stream>>>(rp + 1, partials, N);
    build_col_kernel<<<NBUCKET, 256, 0, stream>>>(rp, bcnt, bstore, col, N);

    constexpr int NPB = 16;  // 100000 % 16 == 0
    const __hip_bfloat162* bufX2 = (const __hip_bfloat162*)bufX;
    const float2* asrc2 = (const float2*)asrc;
    const float2* adst2 = (const float2*)adst;

    // layer 0
    gemm_alpha_v2<128, NPB><<<N / NPB, 64, 0, stream>>>(x, W0, as0, ad0, bufX, asrc, adst);
    aggregate_relu_v4<<<N, 64, 0, stream>>>(bufX2, asrc2, adst2, rp, col, b0, bufH);
    // layer 1
    gemm_alpha_v2<128, NPB><<<N / NPB, 64, 0, stream>>>(bufH, W1, as1, ad1, bufX, asrc, adst);
    aggregate_relu_v4<<<N, 64, 0, stream>>>(bufX2, asrc2, adst2, rp, col, b1, bufH);
    // layer 2
    gemm_alpha_v2<128, NPB><<<N / NPB, 64, 0, stream>>>(bufH, W2, as2, ad2, bufX, asrc, adst);
    aggregate_relu_v4<<<N, 64, 0, stream>>>(bufX2, asrc2, adst2, rp, col, b2, bufH);
    // layer 3
    gemm_alpha_v2<64, NPB><<<N / NPB, 64, 0, stream>>>(bufH, W3, as3, ad3, bufX, asrc, adst);
    aggregate_final_v4<<<N, 64, 0, stream>>>(bufX, asrc2, adst2, rp, col, b3, out);
}

// Round 6
// 562.134 us; speedup vs baseline: 2.2879x; 1.1461x over previous
//
#include <hip/hip_runtime.h>
#include <hip/hip_bf16.h>
#include <math.h>

#define N_NODES 100000
#define N_EDGES 1600000

constexpr int SCAN_B = 1024;

// bucketed CSR build params
constexpr int BSHIFT = 9, BMASK = 511;           // 512 nodes per bucket
constexpr int NBUCKET = (N_NODES + 511) / 512;   // 196
constexpr int BCAP = 16384;                      // entries per bucket (mean 8192)
constexpr int CAPB = 12288;                      // LDS col staging entries
constexpr int EPT = 16, BIN_T = 256, BIN_CHUNK = BIN_T * EPT;  // 4096 edges/block

typedef __attribute__((ext_vector_type(8))) short bf16x8;
typedef __attribute__((ext_vector_type(4))) float f32x4;

__device__ __forceinline__ unsigned short f2bf(float f) {
    unsigned int u = __float_as_uint(f);
    unsigned int r = (u + 0x7fff + ((u >> 16) & 1)) >> 16;  // RNE, finite inputs
    return (unsigned short)r;
}

// ---------------- CSR build (bucketed, low write-amplification) ----------------

__global__ __launch_bounds__(BIN_T) void bin_kernel(const int* __restrict__ src,
                                                    const int* __restrict__ dst,
                                                    int* __restrict__ bcnt,
                                                    unsigned int* __restrict__ bstore, int E) {
    __shared__ int cnt[NBUCKET];
    __shared__ int base[NBUCKET];
    int t = threadIdx.x;
    for (int i = t; i < NBUCKET; i += BIN_T) cnt[i] = 0;
    __syncthreads();
    int e0 = blockIdx.x * BIN_CHUNK;
    int ssrc[EPT], sdst[EPT];
#pragma unroll
    for (int k = 0; k < EPT; ++k) {
        int e = e0 + t + k * BIN_T;
        if (e < E) {
            ssrc[k] = src[e];
            sdst[k] = dst[e];
            atomicAdd(&cnt[sdst[k] >> BSHIFT], 1);
        } else {
            sdst[k] = -1;
        }
    }
    __syncthreads();
    for (int i = t; i < NBUCKET; i += BIN_T) {
        base[i] = atomicAdd(&bcnt[i], cnt[i]);
        cnt[i] = 0;
    }
    __syncthreads();
#pragma unroll
    for (int k = 0; k < EPT; ++k) {
        if (sdst[k] >= 0) {
            int b = sdst[k] >> BSHIFT;
            int off = base[b] + atomicAdd(&cnt[b], 1);
            if (off < BCAP)
                bstore[(size_t)b * BCAP + off] =
                    ((unsigned)ssrc[k] << BSHIFT) | (unsigned)(sdst[k] & BMASK);
        }
    }
}

__global__ __launch_bounds__(256) void deg_from_buckets(const int* __restrict__ bcnt,
                                                        const unsigned int* __restrict__ bstore,
                                                        int* __restrict__ deg, int N) {
    __shared__ int dcnt[512];
    int b = blockIdx.x, t = threadIdx.x;
    for (int i = t; i < 512; i += 256) dcnt[i] = 0;
    __syncthreads();
    int cnt = min(bcnt[b], BCAP);
    for (int i = t; i < cnt; i += 256)
        atomicAdd(&dcnt[bstore[(size_t)b * BCAP + i] & BMASK], 1);
    __syncthreads();
    int nodeBase = b << BSHIFT;
    for (int i = t; i < 512; i += 256)
        if (nodeBase + i < N) deg[nodeBase + i] = dcnt[i];
}

__global__ void scan_block_kernel(const int* __restrict__ in, int* __restrict__ out,
                                  int* __restrict__ partials, int n) {
    __shared__ int sh[SCAN_B];
    int gid = blockIdx.x * SCAN_B + threadIdx.x;
    int v = (gid < n) ? in[gid] : 0;
    sh[threadIdx.x] = v;
    __syncthreads();
    for (int off = 1; off < SCAN_B; off <<= 1) {
        int x = (threadIdx.x >= (unsigned)off) ? sh[threadIdx.x - off] : 0;
        __syncthreads();
        sh[threadIdx.x] += x;
        __syncthreads();
    }
    if (gid < n) out[gid] = sh[threadIdx.x];
    if (threadIdx.x == SCAN_B - 1) partials[blockIdx.x] = sh[SCAN_B - 1];
}

__global__ void scan_partials_kernel(int* partials, int nb) {
    __shared__ int sh[SCAN_B];
    int v = (threadIdx.x < (unsigned)nb) ? partials[threadIdx.x] : 0;
    sh[threadIdx.x] = v;
    __syncthreads();
    for (int off = 1; off < SCAN_B; off <<= 1) {
        int x = (threadIdx.x >= (unsigned)off) ? sh[threadIdx.x - off] : 0;
        __syncthreads();
        sh[threadIdx.x] += x;
        __syncthreads();
    }
    if (threadIdx.x < (unsigned)nb) partials[threadIdx.x] = sh[threadIdx.x] - v; // exclusive
}

__global__ void scan_add_kernel(int* out, const int* __restrict__ partials, int n) {
    int gid = blockIdx.x * SCAN_B + threadIdx.x;
    if (gid < n) out[gid] += partials[blockIdx.x];
}

__global__ __launch_bounds__(256) void build_col_kernel(const int* __restrict__ rp,
                                                        const int* __restrict__ bcnt,
                                                        const unsigned int* __restrict__ bstore,
                                                        int* __restrict__ col, int N) {
    __shared__ int colStage[CAPB];
    __shared__ int rpL[513];
    __shared__ int fillL[512];
    int b = blockIdx.x, t = threadIdx.x;
    int nodeBase = b << BSHIFT;
    int nNodes = min(512, N - nodeBase);
    for (int i = t; i <= nNodes; i += 256) rpL[i] = rp[nodeBase + i];
    for (int i = t; i < nNodes; i += 256) fillL[i] = 0;
    __syncthreads();
    int segBase = rpL[0];
    int segLen = rpL[nNodes] - segBase;
    int cnt = min(bcnt[b], BCAP);
    for (int i = t; i < cnt; i += 256) {
        unsigned e = bstore[(size_t)b * BCAP + i];
        int dl = e & BMASK;
        int sv = (int)(e >> BSHIFT);
        int pos = (rpL[dl] - segBase) + atomicAdd(&fillL[dl], 1);
        if (pos < CAPB) colStage[pos] = sv;
        else col[segBase + pos] = sv;   // overflow fallback
    }
    __syncthreads();
    int lim = min(segLen, CAPB);
    for (int i = t; i < lim; i += 256) col[segBase + i] = colStage[i];
}

// ---------------- W transpose + bf16 cast (once per layer per launch) ----------------
// Wt[c][k] = bf16(W[k][c]); K=128 fixed; thread handles 2 consecutive k -> 1 uint.
__global__ void transpose_w_kernel(const float* __restrict__ W, unsigned int* __restrict__ Wt, int C) {
    int idx = blockIdx.x * blockDim.x + threadIdx.x;   // over C*64
    if (idx >= C * 64) return;
    int c = idx >> 6, kk = idx & 63;
    float w0 = W[(2 * kk) * C + c];
    float w1 = W[(2 * kk + 1) * C + c];
    Wt[c * 64 + kk] = (unsigned)f2bf(w0) | ((unsigned)f2bf(w1) << 16);
}

// ---------------- per-layer GEMM via MFMA + attention dots ----------------
// 1 wave / block, 16 nodes. A = h rows (bf16, LDS-staged), B = Wt cols.
// D tile layout (m89): col = lane&15, row = (lane>>4)*4 + reg.

template<int HD>
__global__ __launch_bounds__(64) void gemm_alpha_mfma(
    const float* __restrict__ h, const unsigned short* __restrict__ Wt,
    const float* __restrict__ a_s, const float* __restrict__ a_d,
    __hip_bfloat16* __restrict__ xl, float* __restrict__ asrc, float* __restrict__ adst) {
    constexpr int NT = HD / 16;       // output col tiles (8 or 4)
    constexpr int GR = HD / 4;        // float4 groups per out row
    int node0 = blockIdx.x * 16;
    int t = threadIdx.x;
    int lan = t & 15, grp = t >> 4;

    __shared__ unsigned short hb[16][136];   // 16 rows x 128 bf16, +8 pad (2-way banks)
    __shared__ float ob[16][HD + 4];         // D staging for transpose

    // stage h -> bf16 LDS: 16 rows x 32 float4 = 512 items, 8 iters
    const float4* h4 = (const float4*)h;
#pragma unroll
    for (int it = 0; it < 8; ++it) {
        int idx = it * 64 + t;
        int nn = idx >> 5, kk = idx & 31;
        float4 v = h4[(size_t)(node0 + nn) * 32 + kk];
        ushort4 u;
        u.x = f2bf(v.x); u.y = f2bf(v.y); u.z = f2bf(v.z); u.w = f2bf(v.w);
        *(ushort4*)&hb[nn][kk * 4] = u;
    }
    __syncthreads();

    // A frags: lane holds row lan, k = ks*32 + grp*8 .. +8
    bf16x8 af[4];
#pragma unroll
    for (int ks = 0; ks < 4; ++ks)
        af[ks] = *(const bf16x8*)&hb[lan][ks * 32 + grp * 8];

    f32x4 acc[NT];
#pragma unroll
    for (int i = 0; i < NT; ++i) acc[i] = (f32x4){0.f, 0.f, 0.f, 0.f};

#pragma unroll
    for (int ks = 0; ks < 4; ++ks) {
        bf16x8 bf[NT];
#pragma unroll
        for (int nt = 0; nt < NT; ++nt)
            bf[nt] = *(const bf16x8*)(Wt + (size_t)(nt * 16 + lan) * 128 + ks * 32 + grp * 8);
#pragma unroll
        for (int nt = 0; nt < NT; ++nt)
            acc[nt] = __builtin_amdgcn_mfma_f32_16x16x32_bf16(af[ks], bf[nt], acc[nt], 0, 0, 0);
    }

    // attention dots: psum[head][j] = sum_c acc*a_s over this lane's col, reduce 16 lanes
    float av[NT], dv[NT];
#pragma unroll
    for (int nt = 0; nt < NT; ++nt) {
        av[nt] = a_s[nt * 16 + lan];
        dv[nt] = a_d[nt * 16 + lan];
    }
    float psum[2][4] = {{0.f,0.f,0.f,0.f},{0.f,0.f,0.f,0.f}};
    float pdum[2][4] = {{0.f,0.f,0.f,0.f},{0.f,0.f,0.f,0.f}};
#pragma unroll
    for (int nt = 0; nt < NT; ++nt) {
        int hs = (nt >= NT / 2) ? 1 : 0;
#pragma unroll
        for (int j = 0; j < 4; ++j) {
            psum[hs][j] = fmaf(acc[nt][j], av[nt], psum[hs][j]);
            pdum[hs][j] = fmaf(acc[nt][j], dv[nt], pdum[hs][j]);
        }
    }
#pragma unroll
    for (int off = 1; off <= 8; off <<= 1) {
#pragma unroll
        for (int hs = 0; hs < 2; ++hs)
#pragma unroll
            for (int j = 0; j < 4; ++j) {
                psum[hs][j] += __shfl_xor(psum[hs][j], off, 64);
                pdum[hs][j] += __shfl_xor(pdum[hs][j], off, 64);
            }
    }
    if (lan == 0) {
#pragma unroll
        for (int j = 0; j < 4; ++j) {
            int node = node0 + grp * 4 + j;
            asrc[node * 2 + 0] = psum[0][j];
            asrc[node * 2 + 1] = psum[1][j];
            adst[node * 2 + 0] = pdum[0][j];
            adst[node * 2 + 1] = pdum[1][j];
        }
    }

    // transpose D through LDS, emit xl bf16 packed
#pragma unroll
    for (int nt = 0; nt < NT; ++nt)
#pragma unroll
        for (int j = 0; j < 4; ++j)
            ob[grp * 4 + j][nt * 16 + lan] = acc[nt][j];
    __syncthreads();
#pragma unroll
    for (int it = 0; it < 16 * GR / 64; ++it) {
        int idx = it * 64 + t;
        int nn = idx / GR, g = idx % GR;
        float4 v = *(const float4*)&ob[nn][g * 4];
        uint2 u;
        u.x = (unsigned)f2bf(v.x) | ((unsigned)f2bf(v.y) << 16);
        u.y = (unsigned)f2bf(v.z) | ((unsigned)f2bf(v.w) << 16);
        ((uint2*)xl)[(size_t)(node0 + nn) * GR + g] = u;
    }
}

// ---------------- aggregation v4 (unchanged) ----------------

__global__ void aggregate_relu_v4(const __hip_bfloat162* __restrict__ xl2,
                                  const float2* __restrict__ a_src, const float2* __restrict__ a_dst,
                                  const int* __restrict__ rp, const int* __restrict__ col,
                                  const float* __restrict__ bias, float* __restrict__ out) {
    int node = blockIdx.x;
    int t = threadIdx.x;           // 0..63
    int head = t >> 5;
    int beg = rp[node], deg = rp[node + 1] - beg;
    float2 adn = a_dst[node];

    __shared__ int   snS[64];
    __shared__ float pS[2][64];

    float s0 = 0.f, s1 = 0.f;
    float ax0 = 0.f, ay0 = 0.f, ax1 = 0.f, ay1 = 0.f;
    float ax2 = 0.f, ay2 = 0.f, ax3 = 0.f, ay3 = 0.f;

    if (deg <= 64) {
        float e0 = -INFINITY, e1 = -INFINITY;
        if (t < deg) {
            int sn = col[beg + t];
            snS[t] = sn;
            float2 a = a_src[sn];
            e0 = a.x + adn.x; e0 = (e0 >= 0.f) ? e0 : 0.2f * e0;
            e1 = a.y + adn.y; e1 = (e1 >= 0.f) ? e1 : 0.2f * e1;
        }
        float m0 = e0, m1 = e1;
#pragma unroll
        for (int off = 32; off >= 1; off >>= 1) {
            m0 = fmaxf(m0, __shfl_xor(m0, off, 64));
            m1 = fmaxf(m1, __shfl_xor(m1, off, 64));
        }
        if (t < deg) {
            float p0 = __expf(e0 - m0), p1 = __expf(e1 - m1);
            pS[0][t] = p0; pS[1][t] = p1;
            s0 = p0; s1 = p1;
        }
        __syncthreads();
        int j = 0;
        for (; j + 8 <= deg; j += 8) {
            int sa = snS[j+0], sb = snS[j+1], sc = snS[j+2], sd = snS[j+3];
            int se = snS[j+4], sf = snS[j+5], sg = snS[j+6], sh = snS[j+7];
            float pa = pS[head][j+0], pb = pS[head][j+1], pc = pS[head][j+2], pd = pS[head][j+3];
            float pe = pS[head][j+4], pf = pS[head][j+5], pg = pS[head][j+6], ph = pS[head][j+7];
            __hip_bfloat162 va = xl2[(size_t)sa * 64 + t];
            __hip_bfloat162 vb = xl2[(size_t)sb * 64 + t];
            __hip_bfloat162 vc = xl2[(size_t)sc * 64 + t];
            __hip_bfloat162 vd = xl2[(size_t)sd * 64 + t];
            __hip_bfloat162 ve = xl2[(size_t)se * 64 + t];
            __hip_bfloat162 vf = xl2[(size_t)sf * 64 + t];
            __hip_bfloat162 vg = xl2[(size_t)sg * 64 + t];
            __hip_bfloat162 vh = xl2[(size_t)sh * 64 + t];
            ax0 = fmaf(pa, __bfloat162float(va.x), ax0); ay0 = fmaf(pa, __bfloat162float(va.y), ay0);
            ax1 = fmaf(pb, __bfloat162float(vb.x), ax1); ay1 = fmaf(pb, __bfloat162float(vb.y), ay1);
            ax2 = fmaf(pc, __bfloat162float(vc.x), ax2); ay2 = fmaf(pc, __bfloat162float(vc.y), ay2);
            ax3 = fmaf(pd, __bfloat162float(vd.x), ax3); ay3 = fmaf(pd, __bfloat162float(vd.y), ay3);
            ax0 = fmaf(pe, __bfloat162float(ve.x), ax0); ay0 = fmaf(pe, __bfloat162float(ve.y), ay0);
            ax1 = fmaf(pf, __bfloat162float(vf.x), ax1); ay1 = fmaf(pf, __bfloat162float(vf.y), ay1);
            ax2 = fmaf(pg, __bfloat162float(vg.x), ax2); ay2 = fmaf(pg, __bfloat162float(vg.y), ay2);
            ax3 = fmaf(ph, __bfloat162float(vh.x), ax3); ay3 = fmaf(ph, __bfloat162float(vh.y), ay3);
        }
        for (; j < deg; ++j) {
            int sn = snS[j];
            float p = pS[head][j];
            __hip_bfloat162 v = xl2[(size_t)sn * 64 + t];
            ax0 = fmaf(p, __bfloat162float(v.x), ax0);
            ay0 = fmaf(p, __bfloat162float(v.y), ay0);
        }
    } else {
        float m0 = -INFINITY, m1 = -INFINITY;
        for (int j = t; j < deg; j += 64) {
            float2 a = a_src[col[beg + j]];
            float e0 = a.x + adn.x; e0 = (e0 >= 0.f) ? e0 : 0.2f * e0;
            float e1 = a.y + adn.y; e1 = (e1 >= 0.f) ? e1 : 0.2f * e1;
            m0 = fmaxf(m0, e0); m1 = fmaxf(m1, e1);
        }
#pragma unroll
        for (int off = 32; off >= 1; off >>= 1) {
            m0 = fmaxf(m0, __shfl_xor(m0, off, 64));
            m1 = fmaxf(m1, __shfl_xor(m1, off, 64));
        }
        for (int c0 = 0; c0 < deg; c0 += 64) {
            int csz = min(64, deg - c0);
            if (t < csz) {
                int sn = col[beg + c0 + t];
                float2 a = a_src[sn];
                float e0 = a.x + adn.x; e0 = (e0 >= 0.f) ? e0 : 0.2f * e0;
                float e1 = a.y + adn.y; e1 = (e1 >= 0.f) ? e1 : 0.2f * e1;
                float p0 = __expf(e0 - m0), p1 = __expf(e1 - m1);
                snS[t] = sn; pS[0][t] = p0; pS[1][t] = p1;
                s0 += p0; s1 += p1;
            }
            __syncthreads();
            for (int j = 0; j < csz; ++j) {
                int sn = snS[j];
                float p = pS[head][j];
                __hip_bfloat162 v = xl2[(size_t)sn * 64 + t];
                ax0 = fmaf(p, __bfloat162float(v.x), ax0);
                ay0 = fmaf(p, __bfloat162float(v.y), ay0);
            }
            __syncthreads();
        }
    }
#pragma unroll
    for (int off = 32; off >= 1; off >>= 1) {
        s0 += __shfl_xor(s0, off, 64);
        s1 += __shfl_xor(s1, off, 64);
    }
    float s = head ? s1 : s0;
    float inv = 1.0f / (s + 1e-16f);
    float2 b2 = ((const float2*)bias)[t];
    float ox = fmaxf(fmaf(ax0 + ax1 + ax2 + ax3, inv, b2.x), 0.f);
    float oy = fmaxf(fmaf(ay0 + ay1 + ay2 + ay3, inv, b2.y), 0.f);
    ((float2*)out)[(size_t)node * 64 + t] = make_float2(ox, oy);
}

__global__ void aggregate_final_v4(const __hip_bfloat16* __restrict__ xl,
                                   const float2* __restrict__ a_src, const float2* __restrict__ a_dst,
                                   const int* __restrict__ rp, const int* __restrict__ col,
                                   const float* __restrict__ bias, float* __restrict__ out) {
    int node = blockIdx.x;
    int t = threadIdx.x;  // 0..63
    int head = t >> 5;
    int beg = rp[node], deg = rp[node + 1] - beg;
    float2 adn = a_dst[node];

    __shared__ int   snS[64];
    __shared__ float pS[2][64];

    float s0 = 0.f, s1 = 0.f;
    float a0 = 0.f, a1 = 0.f, a2 = 0.f, a3 = 0.f;

    if (deg <= 64) {
        float e0 = -INFINITY, e1 = -INFINITY;
        if (t < deg) {
            int sn = col[beg + t];
            snS[t] = sn;
            float2 a = a_src[sn];
            e0 = a.x + adn.x; e0 = (e0 >= 0.f) ? e0 : 0.2f * e0;
            e1 = a.y + adn.y; e1 = (e1 >= 0.f) ? e1 : 0.2f * e1;
        }
        float m0 = e0, m1 = e1;
#pragma unroll
        for (int off = 32; off >= 1; off >>= 1) {
            m0 = fmaxf(m0, __shfl_xor(m0, off, 64));
            m1 = fmaxf(m1, __shfl_xor(m1, off, 64));
        }
        if (t < deg) {
            float p0 = __expf(e0 - m0), p1 = __expf(e1 - m1);
            pS[0][t] = p0; pS[1][t] = p1;
            s0 = p0; s1 = p1;
        }
        __syncthreads();
        int j = 0;
        for (; j + 8 <= deg; j += 8) {
            int sa = snS[j+0], sb = snS[j+1], sc = snS[j+2], sd = snS[j+3];
            int se = snS[j+4], sf = snS[j+5], sg = snS[j+6], sh = snS[j+7];
            float pa = pS[head][j+0], pb = pS[head][j+1], pc = pS[head][j+2], pd = pS[head][j+3];
            float pe = pS[head][j+4], pf = pS[head][j+5], pg = pS[head][j+6], ph = pS[head][j+7];
            float va = __bfloat162float(xl[(size_t)sa * 64 + t]);
            float vb = __bfloat162float(xl[(size_t)sb * 64 + t]);
            float vc = __bfloat162float(xl[(size_t)sc * 64 + t]);
            float vd = __bfloat162float(xl[(size_t)sd * 64 + t]);
            float ve = __bfloat162float(xl[(size_t)se * 64 + t]);
            float vf = __bfloat162float(xl[(size_t)sf * 64 + t]);
            float vg = __bfloat162float(xl[(size_t)sg * 64 + t]);
            float vh = __bfloat162float(xl[(size_t)sh * 64 + t]);
            a0 = fmaf(pa, va, a0); a1 = fmaf(pb, vb, a1);
            a2 = fmaf(pc, vc, a2); a3 = fmaf(pd, vd, a3);
            a0 = fmaf(pe, ve, a0); a1 = fmaf(pf, vf, a1);
            a2 = fmaf(pg, vg, a2); a3 = fmaf(ph, vh, a3);
        }
        for (; j < deg; ++j) {
            a0 = fmaf(pS[head][j], __bfloat162float(xl[(size_t)snS[j] * 64 + t]), a0);
        }
    } else {
        float m0 = -INFINITY, m1 = -INFINITY;
        for (int j = t; j < deg; j += 64) {
            float2 a = a_src[col[beg + j]];
            float e0 = a.x + adn.x; e0 = (e0 >= 0.f) ? e0 : 0.2f * e0;
            float e1 = a.y + adn.y; e1 = (e1 >= 0.f) ? e1 : 0.2f * e1;
            m0 = fmaxf(m0, e0); m1 = fmaxf(m1, e1);
        }
#pragma unroll
        for (int off = 32; off >= 1; off >>= 1) {
            m0 = fmaxf(m0, __shfl_xor(m0, off, 64));
            m1 = fmaxf(m1, __shfl_xor(m1, off, 64));
        }
        for (int c0 = 0; c0 < deg; c0 += 64) {
            int csz = min(64, deg - c0);
            if (t < csz) {
                int sn = col[beg + c0 + t];
                float2 a = a_src[sn];
                float e0 = a.x + adn.x; e0 = (e0 >= 0.f) ? e0 : 0.2f * e0;
                float e1 = a.y + adn.y; e1 = (e1 >= 0.f) ? e1 : 0.2f * e1;
                float p0 = __expf(e0 - m0), p1 = __expf(e1 - m1);
                snS[t] = sn; pS[0][t] = p0; pS[1][t] = p1;
                s0 += p0; s1 += p1;
            }
            __syncthreads();
            for (int j = 0; j < csz; ++j) {
                a0 = fmaf(pS[head][j], __bfloat162float(xl[(size_t)snS[j] * 64 + t]), a0);
            }
            __syncthreads();
        }
    }
#pragma unroll
    for (int off = 32; off >= 1; off >>= 1) {
        s0 += __shfl_xor(s0, off, 64);
        s1 += __shfl_xor(s1, off, 64);
    }
    float s = head ? s1 : s0;
    float o = (a0 + a1 + a2 + a3) / (s + 1e-16f);
    float other = __shfl_down(o, 32, 64);
    if (t < 32) {
        float v = 0.5f * (o + other) + bias[t];
        float mx = v;
#pragma unroll
        for (int off = 16; off >= 1; off >>= 1) mx = fmaxf(mx, __shfl_xor(mx, off, 32));
        float ex = __expf(v - mx);
        float sm = ex;
#pragma unroll
        for (int off = 16; off >= 1; off >>= 1) sm += __shfl_xor(sm, off, 32);
        out[(size_t)node * 32 + t] = v - mx - logf(sm);
    }
}

// ---------------- launch ----------------

extern "C" void kernel_launch(void* const* d_in, const int* in_sizes, int n_in,
                              void* d_out, int out_size, void* d_ws, size_t ws_size,
                              hipStream_t stream) {
    const int N = N_NODES, E = N_EDGES;

    const float* x  = (const float*)d_in[0];
    const int*  ei  = (const int*)d_in[1];
    const float* W0 = (const float*)d_in[2];
    const float* as0 = (const float*)d_in[3];
    const float* ad0 = (const float*)d_in[4];
    const float* b0 = (const float*)d_in[5];
    const float* W1 = (const float*)d_in[6];
    const float* as1 = (const float*)d_in[7];
    const float* ad1 = (const float*)d_in[8];
    const float* b1 = (const float*)d_in[9];
    const float* W2 = (const float*)d_in[10];
    const float* as2 = (const float*)d_in[11];
    const float* ad2 = (const float*)d_in[12];
    const float* b2 = (const float*)d_in[13];
    const float* W3 = (const float*)d_in[14];
    const float* as3 = (const float*)d_in[15];
    const float* ad3 = (const float*)d_in[16];
    const float* b3 = (const float*)d_in[17];
    float* out = (float*)d_out;

    const int* srcv = ei;       // edge_index[0]
    const int* dstv = ei + E;   // edge_index[1]

    char* p = (char*)d_ws;
    auto carve = [&](size_t bytes) -> void* {
        void* r = (void*)p;
        p += (bytes + 255) & ~(size_t)255;
        return r;
    };
    int* deg      = (int*)carve((size_t)N * 4);
    int* rp       = (int*)carve((size_t)(N + 1) * 4);
    int* col      = (int*)carve((size_t)E * 4);
    int* partials = (int*)carve((size_t)SCAN_B * 4);
    int* bcnt     = (int*)carve((size_t)NBUCKET * 4);
    unsigned int* bstore = (unsigned int*)carve((size_t)NBUCKET * BCAP * 4);
    __hip_bfloat16* bufX = (__hip_bfloat16*)carve((size_t)N * 128 * 2);  // xl, bf16
    float* bufH   = (float*)carve((size_t)N * 128 * 4);                  // h, fp32
    float* asrc   = (float*)carve((size_t)N * 2 * 4);
    float* adst   = (float*)carve((size_t)N * 2 * 4);
    unsigned short* Wt0 = (unsigned short*)carve((size_t)128 * 128 * 2);
    unsigned short* Wt1 = (unsigned short*)carve((size_t)128 * 128 * 2);
    unsigned short* Wt2 = (unsigned short*)carve((size_t)128 * 128 * 2);
    unsigned short* Wt3 = (unsigned short*)carve((size_t)64 * 128 * 2);

    hipMemsetAsync(bcnt, 0, (size_t)NBUCKET * 4, stream);
    hipMemsetAsync(rp, 0, 4, stream);

    // bf16 transposed weights
    transpose_w_kernel<<<(128 * 64 + 255) / 256, 256, 0, stream>>>(W0, (unsigned int*)Wt0, 128);
    transpose_w_kernel<<<(128 * 64 + 255) / 256, 256, 0, stream>>>(W1, (unsigned int*)Wt1, 128);
    transpose_w_kernel<<<(128 * 64 + 255) / 256, 256, 0, stream>>>(W2, (unsigned int*)Wt2, 128);
    transpose_w_kernel<<<(64 * 64 + 255) / 256, 256, 0, stream>>>(W3, (unsigned int*)Wt3, 64);

    // bucketed CSR build
    bin_kernel<<<(E + BIN_CHUNK - 1) / BIN_CHUNK, BIN_T, 0, stream>>>(srcv, dstv, bcnt, bstore, E);
    deg_from_buckets<<<NBUCKET, 256, 0, stream>>>(bcnt, bstore, deg, N);
    int nb = (N + SCAN_B - 1) / SCAN_B;
    scan_block_kernel<<<nb, SCAN_B, 0, stream>>>(deg, rp + 1, partials, N);
    scan_partials_kernel<<<1, SCAN_B, 0, stream>>>(partials, nb);
    scan_add_kernel<<<nb, SCAN_B, 0, stream>>>(rp + 1, partials, N);
    build_col_kernel<<<NBUCKET, 256, 0, stream>>>(rp, bcnt, bstore, col, N);

    const __hip_bfloat162* bufX2 = (const __hip_bfloat162*)bufX;
    const float2* asrc2 = (const float2*)asrc;
    const float2* adst2 = (const float2*)adst;

    // layer 0
    gemm_alpha_mfma<128><<<N / 16, 64, 0, stream>>>(x, Wt0, as0, ad0, bufX, asrc, adst);
    aggregate_relu_v4<<<N, 64, 0, stream>>>(bufX2, asrc2, adst2, rp, col, b0, bufH);
    // layer 1
    gemm_alpha_mfma<128><<<N / 16, 64, 0, stream>>>(bufH, Wt1, as1, ad1, bufX, asrc, adst);
    aggregate_relu_v4<<<N, 64, 0, stream>>>(bufX2, asrc2, adst2, rp, col, b1, bufH);
    // layer 2
    gemm_alpha_mfma<128><<<N / 16, 64, 0, stream>>>(bufH, Wt2, as2, ad2, bufX, asrc, adst);
    aggregate_relu_v4<<<N, 64, 0, stream>>>(bufX2, asrc2, adst2, rp, col, b2, bufH);
    // layer 3
    gemm_alpha_mfma<64><<<N / 16, 64, 0, stream>>>(bufH, Wt3, as3, ad3, bufX, asrc, adst);
    aggregate_final_v4<<<N, 64, 0, stream>>>(bufX, asrc2, adst2, rp, col, b3, out);
}

// Round 8
// 532.725 us; speedup vs baseline: 2.4142x; 1.0552x over previous
//
#include <hip/hip_runtime.h>
#include <hip/hip_bf16.h>
#include <math.h>

#define N_NODES 100000
#define N_EDGES 1600000

// bucketed CSR build params
constexpr int BSHIFT = 9, BMASK = 511;           // 512 nodes per bucket
constexpr int NBUCKET = (N_NODES + 511) / 512;   // 196
constexpr int BCAP = 16384;                      // entries per bucket (mean 8192)
constexpr int CAPB = 12288;                      // LDS col staging entries
constexpr int EPT = 16, BIN_T = 256, BIN_CHUNK = BIN_T * EPT;  // 4096 edges/block

typedef __attribute__((ext_vector_type(8))) short bf16x8;
typedef __attribute__((ext_vector_type(4))) float f32x4;

__device__ __forceinline__ unsigned short f2bf(float f) {
    unsigned int u = __float_as_uint(f);
    unsigned int r = (u + 0x7fff + ((u >> 16) & 1)) >> 16;  // RNE, finite inputs
    return (unsigned short)r;
}

// ---------------- CSR build (bucketed) ----------------

__global__ __launch_bounds__(BIN_T) void bin_kernel(const int* __restrict__ src,
                                                    const int* __restrict__ dst,
                                                    int* __restrict__ bcnt,
                                                    unsigned int* __restrict__ bstore, int E) {
    __shared__ int cnt[NBUCKET];
    __shared__ int base[NBUCKET];
    int t = threadIdx.x;
    for (int i = t; i < NBUCKET; i += BIN_T) cnt[i] = 0;
    __syncthreads();
    int e0 = blockIdx.x * BIN_CHUNK;
    int ssrc[EPT], sdst[EPT];
#pragma unroll
    for (int k = 0; k < EPT; ++k) {
        int e = e0 + t + k * BIN_T;
        if (e < E) {
            ssrc[k] = src[e];
            sdst[k] = dst[e];
            atomicAdd(&cnt[sdst[k] >> BSHIFT], 1);
        } else {
            sdst[k] = -1;
        }
    }
    __syncthreads();
    for (int i = t; i < NBUCKET; i += BIN_T) {
        base[i] = atomicAdd(&bcnt[i], cnt[i]);
        cnt[i] = 0;
    }
    __syncthreads();
#pragma unroll
    for (int k = 0; k < EPT; ++k) {
        if (sdst[k] >= 0) {
            int b = sdst[k] >> BSHIFT;
            int off = base[b] + atomicAdd(&cnt[b], 1);
            if (off < BCAP)
                bstore[(size_t)b * BCAP + off] =
                    ((unsigned)ssrc[k] << BSHIFT) | (unsigned)(sdst[k] & BMASK);
        }
    }
}

// 1-block inclusive scan of bucket counts -> bbase[0..NBUCKET]
__global__ __launch_bounds__(256) void scan_bcnt_kernel(const int* __restrict__ bcnt,
                                                        int* __restrict__ bbase) {
    __shared__ int sh[256];
    int t = threadIdx.x;
    int v = (t < NBUCKET) ? min(bcnt[t], BCAP) : 0;
    sh[t] = v;
    __syncthreads();
    for (int off = 1; off < 256; off <<= 1) {
        int x = (t >= off) ? sh[t - off] : 0;
        __syncthreads();
        sh[t] += x;
        __syncthreads();
    }
    if (t < NBUCKET) bbase[t + 1] = sh[t];
    if (t == 0) bbase[0] = 0;
}

// Per bucket: LDS histogram -> in-LDS scan -> write rp; stage col in LDS -> coalesced write.
__global__ __launch_bounds__(256) void build_col_v2(const int* __restrict__ bcnt,
                                                    const int* __restrict__ bbase,
                                                    const unsigned int* __restrict__ bstore,
                                                    int* __restrict__ rp, int* __restrict__ col,
                                                    int N) {
    __shared__ int sA[512], sB[512];
    __shared__ int lofs[513];
    __shared__ int colStage[CAPB];
    int b = blockIdx.x, t = threadIdx.x;
    int nodeBase = b << BSHIFT;
    int nNodes = min(512, N - nodeBase);
    for (int i = t; i < 512; i += 256) sA[i] = 0;
    __syncthreads();
    int cnt = min(bcnt[b], BCAP);
    size_t sbase = (size_t)b * BCAP;
    for (int i = t; i < cnt; i += 256) atomicAdd(&sA[bstore[sbase + i] & BMASK], 1);
    __syncthreads();
    // ping-pong inclusive scan of 512 with 256 threads
    int* srcp = sA; int* dstp = sB;
    for (int off = 1; off < 512; off <<= 1) {
        for (int i = t; i < 512; i += 256) dstp[i] = srcp[i] + ((i >= off) ? srcp[i - off] : 0);
        __syncthreads();
        int* tmp = srcp; srcp = dstp; dstp = tmp;
    }
    for (int i = t; i < 512; i += 256) lofs[i + 1] = srcp[i];
    if (t == 0) lofs[0] = 0;
    // reuse dstp as fill counters
    for (int i = t; i < 512; i += 256) dstp[i] = 0;
    __syncthreads();
    int gbase = bbase[b];
    for (int i = t; i < nNodes; i += 256) rp[nodeBase + i] = gbase + lofs[i];
    if (b == NBUCKET - 1 && t == 0) rp[N] = gbase + lofs[nNodes];
    for (int i = t; i < cnt; i += 256) {
        unsigned e = bstore[sbase + i];
        int dl = e & BMASK;
        int sv = (int)(e >> BSHIFT);
        int pos = lofs[dl] + atomicAdd(&dstp[dl], 1);
        if (pos < CAPB) colStage[pos] = sv;
        else col[gbase + pos] = sv;   // overflow fallback
    }
    __syncthreads();
    int lim = min(cnt, CAPB);
    for (int i = t; i < lim; i += 256) col[gbase + i] = colStage[i];
}

// ---------------- merged W transpose + bf16 cast ----------------
// Wt[c][k] = bf16(W[k][c]); thread handles 2 consecutive k -> 1 uint.
__global__ __launch_bounds__(256) void transpose_all_w(
    const float* __restrict__ W0, const float* __restrict__ W1,
    const float* __restrict__ W2, const float* __restrict__ W3,
    unsigned int* __restrict__ Wt0, unsigned int* __restrict__ Wt1,
    unsigned int* __restrict__ Wt2, unsigned int* __restrict__ Wt3) {
    int idx = blockIdx.x * 256 + threadIdx.x;
    const float* W; unsigned int* Wt; int C, base;
    if (idx < 8192)       { W = W0; Wt = Wt0; C = 128; base = 0; }
    else if (idx < 16384) { W = W1; Wt = Wt1; C = 128; base = 8192; }
    else if (idx < 24576) { W = W2; Wt = Wt2; C = 128; base = 16384; }
    else if (idx < 28672) { W = W3; Wt = Wt3; C = 64;  base = 24576; }
    else return;
    int l = idx - base;
    int c = l >> 6, kk = l & 63;
    float w0 = W[(2 * kk) * C + c];
    float w1 = W[(2 * kk + 1) * C + c];
    Wt[c * 64 + kk] = (unsigned)f2bf(w0) | ((unsigned)f2bf(w1) << 16);
}

// ---------------- per-layer GEMM via MFMA + attention dots ----------------
// 1 wave / block, 16 nodes. F32IN: stage fp32 h via LDS; else direct bf16 loads.
// D tile layout (m89): col = lane&15, row = (lane>>4)*4 + reg.

template<int HD, bool F32IN>
__global__ __launch_bounds__(64) void gemm_alpha_mfma(
    const void* __restrict__ hsrc, const unsigned short* __restrict__ Wt,
    const float* __restrict__ a_s, const float* __restrict__ a_d,
    __hip_bfloat16* __restrict__ xl, float* __restrict__ asrc, float* __restrict__ adst) {
    constexpr int NT = HD / 16;       // output col tiles (8 or 4)
    constexpr int GR = HD / 4;        // uint2 groups per out row
    int node0 = blockIdx.x * 16;
    int t = threadIdx.x;
    int lan = t & 15, grp = t >> 4;

    __shared__ float ob[16][HD + 4];  // D staging for transpose

    bf16x8 af[4];
    if constexpr (F32IN) {
        __shared__ unsigned short hb[16][136];
        const float4* h4 = (const float4*)hsrc;
#pragma unroll
        for (int it = 0; it < 8; ++it) {
            int idx = it * 64 + t;
            int nn = idx >> 5, kk = idx & 31;
            float4 v = h4[(size_t)(node0 + nn) * 32 + kk];
            ushort4 u;
            u.x = f2bf(v.x); u.y = f2bf(v.y); u.z = f2bf(v.z); u.w = f2bf(v.w);
            *(ushort4*)&hb[nn][kk * 4] = u;
        }
        __syncthreads();
#pragma unroll
        for (int ks = 0; ks < 4; ++ks)
            af[ks] = *(const bf16x8*)&hb[lan][ks * 32 + grp * 8];
    } else {
        const unsigned short* hbf = (const unsigned short*)hsrc;
#pragma unroll
        for (int ks = 0; ks < 4; ++ks)
            af[ks] = *(const bf16x8*)(hbf + (size_t)(node0 + lan) * 128 + ks * 32 + grp * 8);
    }

    f32x4 acc[NT];
#pragma unroll
    for (int i = 0; i < NT; ++i) acc[i] = (f32x4){0.f, 0.f, 0.f, 0.f};

#pragma unroll
    for (int ks = 0; ks < 4; ++ks) {
        bf16x8 bfr[NT];
#pragma unroll
        for (int nt = 0; nt < NT; ++nt)
            bfr[nt] = *(const bf16x8*)(Wt + (size_t)(nt * 16 + lan) * 128 + ks * 32 + grp * 8);
#pragma unroll
        for (int nt = 0; nt < NT; ++nt)
            acc[nt] = __builtin_amdgcn_mfma_f32_16x16x32_bf16(af[ks], bfr[nt], acc[nt], 0, 0, 0);
    }

    // attention dots
    float av[NT], dv[NT];
#pragma unroll
    for (int nt = 0; nt < NT; ++nt) {
        av[nt] = a_s[nt * 16 + lan];
        dv[nt] = a_d[nt * 16 + lan];
    }
    float psum[2][4] = {{0.f,0.f,0.f,0.f},{0.f,0.f,0.f,0.f}};
    float pdum[2][4] = {{0.f,0.f,0.f,0.f},{0.f,0.f,0.f,0.f}};
#pragma unroll
    for (int nt = 0; nt < NT; ++nt) {
        int hs = (nt >= NT / 2) ? 1 : 0;
#pragma unroll
        for (int j = 0; j < 4; ++j) {
            psum[hs][j] = fmaf(acc[nt][j], av[nt], psum[hs][j]);
            pdum[hs][j] = fmaf(acc[nt][j], dv[nt], pdum[hs][j]);
        }
    }
#pragma unroll
    for (int off = 1; off <= 8; off <<= 1) {
#pragma unroll
        for (int hs = 0; hs < 2; ++hs)
#pragma unroll
            for (int j = 0; j < 4; ++j) {
                psum[hs][j] += __shfl_xor(psum[hs][j], off, 64);
                pdum[hs][j] += __shfl_xor(pdum[hs][j], off, 64);
            }
    }
    if (lan == 0) {
#pragma unroll
        for (int j = 0; j < 4; ++j) {
            int node = node0 + grp * 4 + j;
            asrc[node * 2 + 0] = psum[0][j];
            asrc[node * 2 + 1] = psum[1][j];
            adst[node * 2 + 0] = pdum[0][j];
            adst[node * 2 + 1] = pdum[1][j];
        }
    }

    // transpose D through LDS, emit xl bf16 packed
#pragma unroll
    for (int nt = 0; nt < NT; ++nt)
#pragma unroll
        for (int j = 0; j < 4; ++j)
            ob[grp * 4 + j][nt * 16 + lan] = acc[nt][j];
    __syncthreads();
#pragma unroll
    for (int it = 0; it < 16 * GR / 64; ++it) {
        int idx = it * 64 + t;
        int nn = idx / GR, g = idx % GR;
        float4 v = *(const float4*)&ob[nn][g * 4];
        uint2 u;
        u.x = (unsigned)f2bf(v.x) | ((unsigned)f2bf(v.y) << 16);
        u.y = (unsigned)f2bf(v.z) | ((unsigned)f2bf(v.w) << 16);
        ((uint2*)xl)[(size_t)(node0 + nn) * GR + g] = u;
    }
}

// ---------------- aggregation v5: bf16 gather, bf16 packed output ----------------

__global__ void aggregate_relu_v5(const __hip_bfloat162* __restrict__ xl2,
                                  const float2* __restrict__ a_src, const float2* __restrict__ a_dst,
                                  const int* __restrict__ rp, const int* __restrict__ col,
                                  const float* __restrict__ bias, unsigned int* __restrict__ out) {
    int node = blockIdx.x;
    int t = threadIdx.x;           // 0..63
    int head = t >> 5;
    int beg = rp[node], deg = rp[node + 1] - beg;
    float2 adn = a_dst[node];

    __shared__ int   snS[64];
    __shared__ float pS[2][64];

    float s0 = 0.f, s1 = 0.f;
    float ax0 = 0.f, ay0 = 0.f, ax1 = 0.f, ay1 = 0.f;
    float ax2 = 0.f, ay2 = 0.f, ax3 = 0.f, ay3 = 0.f;

    if (deg <= 64) {
        float e0 = -INFINITY, e1 = -INFINITY;
        if (t < deg) {
            int sn = col[beg + t];
            snS[t] = sn;
            float2 a = a_src[sn];
            e0 = a.x + adn.x; e0 = (e0 >= 0.f) ? e0 : 0.2f * e0;
            e1 = a.y + adn.y; e1 = (e1 >= 0.f) ? e1 : 0.2f * e1;
        }
        float m0 = e0, m1 = e1;
#pragma unroll
        for (int off = 32; off >= 1; off >>= 1) {
            m0 = fmaxf(m0, __shfl_xor(m0, off, 64));
            m1 = fmaxf(m1, __shfl_xor(m1, off, 64));
        }
        if (t < deg) {
            float p0 = __expf(e0 - m0), p1 = __expf(e1 - m1);
            pS[0][t] = p0; pS[1][t] = p1;
            s0 = p0; s1 = p1;
        }
        __syncthreads();
        int j = 0;
        for (; j + 8 <= deg; j += 8) {
            int sa = snS[j+0], sb = snS[j+1], sc = snS[j+2], sd = snS[j+3];
            int se = snS[j+4], sf = snS[j+5], sg = snS[j+6], sh = snS[j+7];
            float pa = pS[head][j+0], pb = pS[head][j+1], pc = pS[head][j+2], pd = pS[head][j+3];
            float pe = pS[head][j+4], pf = pS[head][j+5], pg = pS[head][j+6], ph = pS[head][j+7];
            __hip_bfloat162 va = xl2[(size_t)sa * 64 + t];
            __hip_bfloat162 vb = xl2[(size_t)sb * 64 + t];
            __hip_bfloat162 vc = xl2[(size_t)sc * 64 + t];
            __hip_bfloat162 vd = xl2[(size_t)sd * 64 + t];
            __hip_bfloat162 ve = xl2[(size_t)se * 64 + t];
            __hip_bfloat162 vf = xl2[(size_t)sf * 64 + t];
            __hip_bfloat162 vg = xl2[(size_t)sg * 64 + t];
            __hip_bfloat162 vh = xl2[(size_t)sh * 64 + t];
            ax0 = fmaf(pa, __bfloat162float(va.x), ax0); ay0 = fmaf(pa, __bfloat162float(va.y), ay0);
            ax1 = fmaf(pb, __bfloat162float(vb.x), ax1); ay1 = fmaf(pb, __bfloat162float(vb.y), ay1);
            ax2 = fmaf(pc, __bfloat162float(vc.x), ax2); ay2 = fmaf(pc, __bfloat162float(vc.y), ay2);
            ax3 = fmaf(pd, __bfloat162float(vd.x), ax3); ay3 = fmaf(pd, __bfloat162float(vd.y), ay3);
            ax0 = fmaf(pe, __bfloat162float(ve.x), ax0); ay0 = fmaf(pe, __bfloat162float(ve.y), ay0);
            ax1 = fmaf(pf, __bfloat162float(vf.x), ax1); ay1 = fmaf(pf, __bfloat162float(vf.y), ay1);
            ax2 = fmaf(pg, __bfloat162float(vg.x), ax2); ay2 = fmaf(pg, __bfloat162float(vg.y), ay2);
            ax3 = fmaf(ph, __bfloat162float(vh.x), ax3); ay3 = fmaf(ph, __bfloat162float(vh.y), ay3);
        }
        for (; j < deg; ++j) {
            int sn = snS[j];
            float p = pS[head][j];
            __hip_bfloat162 v = xl2[(size_t)sn * 64 + t];
            ax0 = fmaf(p, __bfloat162float(v.x), ax0);
            ay0 = fmaf(p, __bfloat162float(v.y), ay0);
        }
    } else {
        float m0 = -INFINITY, m1 = -INFINITY;
        for (int j = t; j < deg; j += 64) {
            float2 a = a_src[col[beg + j]];
            float e0 = a.x + adn.x; e0 = (e0 >= 0.f) ? e0 : 0.2f * e0;
            float e1 = a.y + adn.y; e1 = (e1 >= 0.f) ? e1 : 0.2f * e1;
            m0 = fmaxf(m0, e0); m1 = fmaxf(m1, e1);
        }
#pragma unroll
        for (int off = 32; off >= 1; off >>= 1) {
            m0 = fmaxf(m0, __shfl_xor(m0, off, 64));
            m1 = fmaxf(m1, __shfl_xor(m1, off, 64));
        }
        for (int c0 = 0; c0 < deg; c0 += 64) {
            int csz = min(64, deg - c0);
            if (t < csz) {
                int sn = col[beg + c0 + t];
                float2 a = a_src[sn];
                float e0 = a.x + adn.x; e0 = (e0 >= 0.f) ? e0 : 0.2f * e0;
                float e1 = a.y + adn.y; e1 = (e1 >= 0.f) ? e1 : 0.2f * e1;
                float p0 = __expf(e0 - m0), p1 = __expf(e1 - m1);
                snS[t] = sn; pS[0][t] = p0; pS[1][t] = p1;
                s0 += p0; s1 += p1;
            }
            __syncthreads();
            for (int j = 0; j < csz; ++j) {
                int sn = snS[j];
                float p = pS[head][j];
                __hip_bfloat162 v = xl2[(size_t)sn * 64 + t];
                ax0 = fmaf(p, __bfloat162float(v.x), ax0);
                ay0 = fmaf(p, __bfloat162float(v.y), ay0);
            }
            __syncthreads();
        }
    }
#pragma unroll
    for (int off = 32; off >= 1; off >>= 1) {
        s0 += __shfl_xor(s0, off, 64);
        s1 += __shfl_xor(s1, off, 64);
    }
    float s = head ? s1 : s0;
    float inv = 1.0f / (s + 1e-16f);
    float2 b2 = ((const float2*)bias)[t];
    float ox = fmaxf(fmaf(ax0 + ax1 + ax2 + ax3, inv, b2.x), 0.f);
    float oy = fmaxf(fmaf(ay0 + ay1 + ay2 + ay3, inv, b2.y), 0.f);
    out[(size_t)node * 64 + t] = (unsigned)f2bf(ox) | ((unsigned)f2bf(oy) << 16);
}

__global__ void aggregate_final_v4(const __hip_bfloat16* __restrict__ xl,
                                   const float2* __restrict__ a_src, const float2* __restrict__ a_dst,
                                   const int* __restrict__ rp, const int* __restrict__ col,
                                   const float* __restrict__ bias, float* __restrict__ out) {
    int node = blockIdx.x;
    int t = threadIdx.x;  // 0..63
    int head = t >> 5;
    int beg = rp[node], deg = rp[node + 1] - beg;
    float2 adn = a_dst[node];

    __shared__ int   snS[64];
    __shared__ float pS[2][64];

    float s0 = 0.f, s1 = 0.f;
    float a0 = 0.f, a1 = 0.f, a2 = 0.f, a3 = 0.f;

    if (deg <= 64) {
        float e0 = -INFINITY, e1 = -INFINITY;
        if (t < deg) {
            int sn = col[beg + t];
            snS[t] = sn;
            float2 a = a_src[sn];
            e0 = a.x + adn.x; e0 = (e0 >= 0.f) ? e0 : 0.2f * e0;
            e1 = a.y + adn.y; e1 = (e1 >= 0.f) ? e1 : 0.2f * e1;
        }
        float m0 = e0, m1 = e1;
#pragma unroll
        for (int off = 32; off >= 1; off >>= 1) {
            m0 = fmaxf(m0, __shfl_xor(m0, off, 64));
            m1 = fmaxf(m1, __shfl_xor(m1, off, 64));
        }
        if (t < deg) {
            float p0 = __expf(e0 - m0), p1 = __expf(e1 - m1);
            pS[0][t] = p0; pS[1][t] = p1;
            s0 = p0; s1 = p1;
        }
        __syncthreads();
        int j = 0;
        for (; j + 8 <= deg; j += 8) {
            int sa = snS[j+0], sb = snS[j+1], sc = snS[j+2], sd = snS[j+3];
            int se = snS[j+4], sf = snS[j+5], sg = snS[j+6], sh = snS[j+7];
            float pa = pS[head][j+0], pb = pS[head][j+1], pc = pS[head][j+2], pd = pS[head][j+3];
            float pe = pS[head][j+4], pf = pS[head][j+5], pg = pS[head][j+6], ph = pS[head][j+7];
            float va = __bfloat162float(xl[(size_t)sa * 64 + t]);
            float vb = __bfloat162float(xl[(size_t)sb * 64 + t]);
            float vc = __bfloat162float(xl[(size_t)sc * 64 + t]);
            float vd = __bfloat162float(xl[(size_t)sd * 64 + t]);
            float ve = __bfloat162float(xl[(size_t)se * 64 + t]);
            float vf = __bfloat162float(xl[(size_t)sf * 64 + t]);
            float vg = __bfloat162float(xl[(size_t)sg * 64 + t]);
            float vh = __bfloat162float(xl[(size_t)sh * 64 + t]);
            a0 = fmaf(pa, va, a0); a1 = fmaf(pb, vb, a1);
            a2 = fmaf(pc, vc, a2); a3 = fmaf(pd, vd, a3);
            a0 = fmaf(pe, ve, a0); a1 = fmaf(pf, vf, a1);
            a2 = fmaf(pg, vg, a2); a3 = fmaf(ph, vh, a3);
        }
        for (; j < deg; ++j) {
            a0 = fmaf(pS[head][j], __bfloat162float(xl[(size_t)snS[j] * 64 + t]), a0);
        }
    } else {
        float m0 = -INFINITY, m1 = -INFINITY;
        for (int j = t; j < deg; j += 64) {
            float2 a = a_src[col[beg + j]];
            float e0 = a.x + adn.x; e0 = (e0 >= 0.f) ? e0 : 0.2f * e0;
            float e1 = a.y + adn.y; e1 = (e1 >= 0.f) ? e1 : 0.2f * e1;
            m0 = fmaxf(m0, e0); m1 = fmaxf(m1, e1);
        }
#pragma unroll
        for (int off = 32; off >= 1; off >>= 1) {
            m0 = fmaxf(m0, __shfl_xor(m0, off, 64));
            m1 = fmaxf(m1, __shfl_xor(m1, off, 64));
        }
        for (int c0 = 0; c0 < deg; c0 += 64) {
            int csz = min(64, deg - c0);
            if (t < csz) {
                int sn = col[beg + c0 + t];
                float2 a = a_src[sn];
                float e0 = a.x + adn.x; e0 = (e0 >= 0.f) ? e0 : 0.2f * e0;
                float e1 = a.y + adn.y; e1 = (e1 >= 0.f) ? e1 : 0.2f * e1;
                float p0 = __expf(e0 - m0), p1 = __expf(e1 - m1);
                snS[t] = sn; pS[0][t] = p0; pS[1][t] = p1;
                s0 += p0; s1 += p1;
            }
            __syncthreads();
            for (int j = 0; j < csz; ++j) {
                a0 = fmaf(pS[head][j], __bfloat162float(xl[(size_t)snS[j] * 64 + t]), a0);
            }
            __syncthreads();
        }
    }
#pragma unroll
    for (int off = 32; off >= 1; off >>= 1) {
        s0 += __shfl_xor(s0, off, 64);
        s1 += __shfl_xor(s1, off, 64);
    }
    float s = head ? s1 : s0;
    float o = (a0 + a1 + a2 + a3) / (s + 1e-16f);
    float other = __shfl_down(o, 32, 64);
    if (t < 32) {
        float v = 0.5f * (o + other) + bias[t];
        float mx = v;
#pragma unroll
        for (int off = 16; off >= 1; off >>= 1) mx = fmaxf(mx, __shfl_xor(mx, off, 32));
        float ex = __expf(v - mx);
        float sm = ex;
#pragma unroll
        for (int off = 16; off >= 1; off >>= 1) sm += __shfl_xor(sm, off, 32);
        out[(size_t)node * 32 + t] = v - mx - logf(sm);
    }
}

// ---------------- launch ----------------

extern "C" void kernel_launch(void* const* d_in, const int* in_sizes, int n_in,
                              void* d_out, int out_size, void* d_ws, size_t ws_size,
                              hipStream_t stream) {
    const int N = N_NODES, E = N_EDGES;

    const float* x  = (const float*)d_in[0];
    const int*  ei  = (const int*)d_in[1];
    const float* W0 = (const float*)d_in[2];
    const float* as0 = (const float*)d_in[3];
    const float* ad0 = (const float*)d_in[4];
    const float* b0 = (const float*)d_in[5];
    const float* W1 = (const float*)d_in[6];
    const float* as1 = (const float*)d_in[7];
    const float* ad1 = (const float*)d_in[8];
    const float* b1 = (const float*)d_in[9];
    const float* W2 = (const float*)d_in[10];
    const float* as2 = (const float*)d_in[11];
    const float* ad2 = (const float*)d_in[12];
    const float* b2 = (const float*)d_in[13];
    const float* W3 = (const float*)d_in[14];
    const float* as3 = (const float*)d_in[15];
    const float* ad3 = (const float*)d_in[16];
    const float* b3 = (const float*)d_in[17];
    float* out = (float*)d_out;

    const int* srcv = ei;       // edge_index[0]
    const int* dstv = ei + E;   // edge_index[1]

    char* p = (char*)d_ws;
    auto carve = [&](size_t bytes) -> void* {
        void* r = (void*)p;
        p += (bytes + 255) & ~(size_t)255;
        return r;
    };
    int* rp       = (int*)carve((size_t)(N + 1) * 4);
    int* col      = (int*)carve((size_t)E * 4);
    int* bcnt     = (int*)carve((size_t)NBUCKET * 4);
    int* bbase    = (int*)carve((size_t)(NBUCKET + 1) * 4);
    unsigned int* bstore = (unsigned int*)carve((size_t)NBUCKET * BCAP * 4);
    __hip_bfloat16* bufX = (__hip_bfloat16*)carve((size_t)N * 128 * 2);  // xl, bf16
    __hip_bfloat16* bufH = (__hip_bfloat16*)carve((size_t)N * 128 * 2);  // h, bf16
    float* asrc   = (float*)carve((size_t)N * 2 * 4);
    float* adst   = (float*)carve((size_t)N * 2 * 4);
    unsigned short* Wt0 = (unsigned short*)carve((size_t)128 * 128 * 2);
    unsigned short* Wt1 = (unsigned short*)carve((size_t)128 * 128 * 2);
    unsigned short* Wt2 = (unsigned short*)carve((size_t)128 * 128 * 2);
    unsigned short* Wt3 = (unsigned short*)carve((size_t)64 * 128 * 2);

    hipMemsetAsync(bcnt, 0, (size_t)NBUCKET * 4, stream);

    // bf16 transposed weights (one kernel)
    transpose_all_w<<<112, 256, 0, stream>>>(W0, W1, W2, W3,
                                             (unsigned int*)Wt0, (unsigned int*)Wt1,
                                             (unsigned int*)Wt2, (unsigned int*)Wt3);

    // bucketed CSR build
    bin_kernel<<<(E + BIN_CHUNK - 1) / BIN_CHUNK, BIN_T, 0, stream>>>(srcv, dstv, bcnt, bstore, E);
    scan_bcnt_kernel<<<1, 256, 0, stream>>>(bcnt, bbase);
    build_col_v2<<<NBUCKET, 256, 0, stream>>>(bcnt, bbase, bstore, rp, col, N);

    const __hip_bfloat162* bufX2 = (const __hip_bfloat162*)bufX;
    const float2* asrc2 = (const float2*)asrc;
    const float2* adst2 = (const float2*)adst;

    // layer 0 (fp32 input)
    gemm_alpha_mfma<128, true><<<N / 16, 64, 0, stream>>>(x, Wt0, as0, ad0, bufX, asrc, adst);
    aggregate_relu_v5<<<N, 64, 0, stream>>>(bufX2, asrc2, adst2, rp, col, b0, (unsigned int*)bufH);
    // layer 1 (bf16 input)
    gemm_alpha_mfma<128, false><<<N / 16, 64, 0, stream>>>(bufH, Wt1, as1, ad1, bufX, asrc, adst);
    aggregate_relu_v5<<<N, 64, 0, stream>>>(bufX2, asrc2, adst2, rp, col, b1, (unsigned int*)bufH);
    // layer 2
    gemm_alpha_mfma<128, false><<<N / 16, 64, 0, stream>>>(bufH, Wt2, as2, ad2, bufX, asrc, adst);
    aggregate_relu_v5<<<N, 64, 0, stream>>>(bufX2, asrc2, adst2, rp, col, b2, (unsigned int*)bufH);
    // layer 3
    gemm_alpha_mfma<64, false><<<N / 16, 64, 0, stream>>>(bufH, Wt3, as3, ad3, bufX, asrc, adst);
    aggregate_final_v4<<<N, 64, 0, stream>>>(bufX, asrc2, adst2, rp, col, b3, out);
}